// Round 10
// baseline (164.287 us; speedup 1.0000x reference)
//
#include <hip/hip_runtime.h>
#include <hip/hip_bf16.h>
#include <hip/hip_fp16.h>
#include <math.h>

#define NN 50000
#define EE 800000
#define FIN 256
#define FH 96
#define FC 40
#define NBK 196   // ceil(50000/256) buckets of 256 nodes

typedef _Float16 h4 __attribute__((ext_vector_type(4)));
typedef _Float16 h8 __attribute__((ext_vector_type(8)));
typedef float f32x4 __attribute__((ext_vector_type(4)));

// ---------------- privatized LDS histogram (deg by row, cnt by col) ----------------

__global__ __launch_bounds__(256) void k_hist(const int* __restrict__ ei, int E,
                                              unsigned* __restrict__ copies) {
    __shared__ unsigned hist[12500];
    int b = blockIdx.x;
    int slice = b & 63;
    int half = (b >> 6) & 1;
    int arr = b >> 7;
    const int* ptr = ei + (size_t)arr * E;  // arr=0: row, arr=1: col
    int tid = threadIdx.x;
    for (int i = tid; i < 12500; i += 256) hist[i] = 0u;
    __syncthreads();
    int ES = (E + 63) >> 6;
    int lo = slice * ES, hi = min(lo + ES, E);
    int nlo = half * 25000;
    for (int i = lo + tid; i < hi; i += 256) {
        int rel = ptr[i] - nlo;
        if ((unsigned)rel < 25000u)
            atomicAdd(&hist[rel >> 1], 1u << ((rel & 1) << 4));
    }
    __syncthreads();
    unsigned* dst = copies + (size_t)((arr * 2 + half) * 64 + slice) * 12500;
    for (int i = tid; i < 12500; i += 256) dst[i] = hist[i];
}

// sum the 64 copies -> dinv (float, rsqrt(deg+1)) and cnt (u32)
__global__ void k_reduce(const unsigned* __restrict__ copies,
                         float* __restrict__ dinv, unsigned* __restrict__ cnt) {
    int t = blockIdx.x * blockDim.x + threadIdx.x;  // 0..24999
    if (t >= 25000) return;
    int half = t / 12500, w = t - half * 12500;
    unsigned sr = 0, sc = 0;
    const unsigned* br = copies + (size_t)(half) * 64 * 12500 + w;      // rows
    const unsigned* bc = copies + (size_t)(2 + half) * 64 * 12500 + w;  // cols
#pragma unroll 8
    for (int s = 0; s < 64; ++s) { sr += br[s * 12500]; sc += bc[s * 12500]; }
    int n0 = half * 25000 + 2 * w;
    dinv[n0]     = rsqrtf((float)((sr & 0xffffu) + 1u));
    dinv[n0 + 1] = rsqrtf((float)((sr >> 16) + 1u));
    cnt[n0]     = sc & 0xffffu;
    cnt[n0 + 1] = sc >> 16;
}

// ---------------- exclusive scan of cnt -> off ----------------

__global__ __launch_bounds__(1024) void k_scanA(const unsigned* __restrict__ cnt,
                                                unsigned* __restrict__ off,
                                                unsigned* __restrict__ bsum, int n) {
    __shared__ unsigned s[1024];
    int t = threadIdx.x;
    int i = blockIdx.x * 1024 + t;
    unsigned v = (i < n) ? cnt[i] : 0u;
    s[t] = v;
    __syncthreads();
    for (int o = 1; o < 1024; o <<= 1) {
        unsigned tv = (t >= o) ? s[t - o] : 0u;
        __syncthreads();
        s[t] += tv;
        __syncthreads();
    }
    if (i < n) off[i] = s[t] - v;  // exclusive
    if (t == 1023) bsum[blockIdx.x] = s[1023];
}

__global__ void k_scanB1(unsigned* bsum, int nb) {
    if (threadIdx.x == 0 && blockIdx.x == 0) {
        unsigned run = 0;
        for (int b = 0; b < nb; ++b) { unsigned tv = bsum[b]; bsum[b] = run; run += tv; }
    }
}

// adds block prefix; also initializes gcur[b] = off[b*256]
__global__ void k_scanB2(unsigned* __restrict__ off, const unsigned* __restrict__ bsum,
                         unsigned* __restrict__ gcur, int n, unsigned e) {
    int i = blockIdx.x * blockDim.x + threadIdx.x;
    if (i < n) {
        unsigned v = off[i] + bsum[i >> 10];
        off[i] = v;
        if ((i & 255) == 0) gcur[i >> 8] = v;
    }
    if (i == n) off[n] = e;
}

// ---------------- P1: coarse bucket by col>>8 ----------------

__global__ __launch_bounds__(256) void k_bucket(const int* __restrict__ row,
                                                const int* __restrict__ col,
                                                const float* __restrict__ ew,
                                                unsigned* __restrict__ gcur,
                                                unsigned* __restrict__ bkc,
                                                float2* __restrict__ bkrw, int E) {
    __shared__ unsigned cnt[NBK];
    __shared__ unsigned cur[NBK];
    int tid = threadIdx.x;
    int CH = (E + gridDim.x - 1) / gridDim.x;
    int lo = blockIdx.x * CH, hi = min(lo + CH, E);
    for (int i = tid; i < NBK; i += 256) cnt[i] = 0u;
    __syncthreads();
    for (int i = lo + tid; i < hi; i += 256) atomicAdd(&cnt[col[i] >> 8], 1u);
    __syncthreads();
    for (int i = tid; i < NBK; i += 256) cur[i] = atomicAdd(&gcur[i], cnt[i]);
    __syncthreads();
    for (int i = lo + tid; i < hi; i += 256) {
        int c = col[i];
        unsigned pos = atomicAdd(&cur[c >> 8], 1u);
        bkc[pos] = (unsigned)c;
        float2 p;
        p.x = __int_as_float(row[i]);
        p.y = ew[i];
        bkrw[pos] = p;
    }
}

// ---------------- P2: exact place within bucket ----------------

__global__ __launch_bounds__(256) void k_place(const unsigned* __restrict__ bkc,
                                               const float2* __restrict__ bkrw,
                                               const unsigned* __restrict__ off,
                                               float2* __restrict__ epk, int n) {
    __shared__ unsigned cur[256];
    int b = blockIdx.x;
    int tid = threadIdx.x;
    int node0 = b * 256;
    int node = node0 + tid;
    cur[tid] = off[(node <= n) ? node : n];
    __syncthreads();
    unsigned st = off[node0];
    unsigned en = off[min(node0 + 256, n)];
    for (unsigned i = st + tid; i < en; i += 256) {
        unsigned c = bkc[i];
        unsigned pos = atomicAdd(&cur[c & 255], 1u);
        epk[pos] = bkrw[i];
    }
}

// ---------------- GEMM1 (MFMA fp16): planar halves g0hA (feats 0-47), g0hB (48-95) ----------------

__global__ __launch_bounds__(256) void k_gemm1(const float* __restrict__ x,
                                               const float* __restrict__ W,
                                               const float* __restrict__ dinv,
                                               _Float16* __restrict__ g0hA,
                                               _Float16* __restrict__ g0hB, int n) {
    __shared__ _Float16 xs[64][72];
    __shared__ _Float16 wsm[96][72];
    int tid = threadIdx.x;
    int row0 = blockIdx.x * 64;
    int l = tid & 63, w = tid >> 6;
    int l15 = l & 15, lg = l >> 4;

    f32x4 acc[6];
#pragma unroll
    for (int c = 0; c < 6; ++c) acc[c] = (f32x4)0.f;

    for (int kc = 0; kc < 4; ++kc) {
        int kbase = kc * 64;
#pragma unroll
        for (int i = 0; i < 4; ++i) {
            int it = tid + 256 * i;
            int r = it >> 4, k4 = it & 15;
            float4 v = make_float4(0.f, 0.f, 0.f, 0.f);
            int gr = row0 + r;
            if (gr < n) v = *(const float4*)&x[gr * FIN + kbase + k4 * 4];
            h4 hv = {(_Float16)v.x, (_Float16)v.y, (_Float16)v.z, (_Float16)v.w};
            *(h4*)&xs[r][k4 * 4] = hv;
        }
#pragma unroll
        for (int i = 0; i < 6; ++i) {
            int it = tid + 256 * i;
            int r = it >> 4, k4 = it & 15;
            float4 v = *(const float4*)&W[r * FIN + kbase + k4 * 4];
            h4 hv = {(_Float16)v.x, (_Float16)v.y, (_Float16)v.z, (_Float16)v.w};
            *(h4*)&wsm[r][k4 * 4] = hv;
        }
        __syncthreads();
#pragma unroll
        for (int ks = 0; ks < 2; ++ks) {
            h8 a = *(const h8*)&xs[16 * w + l15][ks * 32 + lg * 8];
#pragma unroll
            for (int ct = 0; ct < 6; ++ct) {
                h8 b = *(const h8*)&wsm[ct * 16 + l15][ks * 32 + lg * 8];
                acc[ct] = __builtin_amdgcn_mfma_f32_16x16x32_f16(a, b, acc[ct], 0, 0, 0);
            }
        }
        __syncthreads();
    }
#pragma unroll
    for (int r = 0; r < 4; ++r) {
        int grow = row0 + 16 * w + lg * 4 + r;
        if (grow < n) {
            float dv = dinv[grow];
#pragma unroll
            for (int ct = 0; ct < 3; ++ct)
                g0hA[(size_t)grow * 48 + ct * 16 + l15] = (_Float16)(dv * acc[ct][r]);
#pragma unroll
            for (int ct = 3; ct < 6; ++ct)
                g0hB[(size_t)grow * 48 + (ct - 3) * 16 + l15] = (_Float16)(dv * acc[ct][r]);
        }
    }
}

// ---------------- aggregation 96, one planar half per launch (12 f4-chunks/node) ----------------
// gpl: planar half (N x 48 fp16); bh: bias + 48*pass; hout: h + 48*pass

__global__ __launch_bounds__(256) void k_agg96(const _Float16* __restrict__ gpl,
                                               const unsigned* __restrict__ off,
                                               const float2* __restrict__ epk,
                                               const float* __restrict__ dinv,
                                               const float* __restrict__ bh,
                                               _Float16* __restrict__ hout, int n) {
    int tid = blockIdx.x * 256 + threadIdx.x;
    int node = tid / 12;
    int f4 = tid - node * 12;
    if (node >= n) return;
    h4 self = ((const h4*)gpl)[(size_t)node * 12 + f4];
    float4 acc = make_float4((float)self[0], (float)self[1], (float)self[2], (float)self[3]);
    unsigned st = off[node], en = off[node + 1];
    unsigned e = st;
    for (; e + 4 <= en; e += 4) {
        float2 p0 = epk[e + 0], p1 = epk[e + 1], p2 = epk[e + 2], p3 = epk[e + 3];
        h4 ga = ((const h4*)gpl)[(size_t)__float_as_int(p0.x) * 12 + f4];
        h4 gb = ((const h4*)gpl)[(size_t)__float_as_int(p1.x) * 12 + f4];
        h4 gc = ((const h4*)gpl)[(size_t)__float_as_int(p2.x) * 12 + f4];
        h4 gd = ((const h4*)gpl)[(size_t)__float_as_int(p3.x) * 12 + f4];
        acc.x = fmaf(p0.y, (float)ga[0], acc.x);
        acc.y = fmaf(p0.y, (float)ga[1], acc.y);
        acc.z = fmaf(p0.y, (float)ga[2], acc.z);
        acc.w = fmaf(p0.y, (float)ga[3], acc.w);
        acc.x = fmaf(p1.y, (float)gb[0], acc.x);
        acc.y = fmaf(p1.y, (float)gb[1], acc.y);
        acc.z = fmaf(p1.y, (float)gb[2], acc.z);
        acc.w = fmaf(p1.y, (float)gb[3], acc.w);
        acc.x = fmaf(p2.y, (float)gc[0], acc.x);
        acc.y = fmaf(p2.y, (float)gc[1], acc.y);
        acc.z = fmaf(p2.y, (float)gc[2], acc.z);
        acc.w = fmaf(p2.y, (float)gc[3], acc.w);
        acc.x = fmaf(p3.y, (float)gd[0], acc.x);
        acc.y = fmaf(p3.y, (float)gd[1], acc.y);
        acc.z = fmaf(p3.y, (float)gd[2], acc.z);
        acc.w = fmaf(p3.y, (float)gd[3], acc.w);
    }
    for (; e < en; ++e) {
        float2 p = epk[e];
        h4 g = ((const h4*)gpl)[(size_t)__float_as_int(p.x) * 12 + f4];
        acc.x = fmaf(p.y, (float)g[0], acc.x);
        acc.y = fmaf(p.y, (float)g[1], acc.y);
        acc.z = fmaf(p.y, (float)g[2], acc.z);
        acc.w = fmaf(p.y, (float)g[3], acc.w);
    }
    float s = dinv[node];
    float4 bv = ((const float4*)bh)[f4];
    h4 o;
    o[0] = (_Float16)fmaxf(fmaf(s, acc.x, bv.x), 0.f);
    o[1] = (_Float16)fmaxf(fmaf(s, acc.y, bv.y), 0.f);
    o[2] = (_Float16)fmaxf(fmaf(s, acc.z, bv.z), 0.f);
    o[3] = (_Float16)fmaxf(fmaf(s, acc.w, bv.w), 0.f);
    *(h4*)&hout[(size_t)node * FH + f4 * 4] = o;
}

// ---------------- GEMM2 (MFMA fp16): g1h = fp16( dinv ⊙ (h @ W2^T) ) ----------------

__global__ __launch_bounds__(256) void k_gemm2(const _Float16* __restrict__ h,
                                               const float* __restrict__ W2,
                                               const float* __restrict__ dinv,
                                               _Float16* __restrict__ g1h, int n) {
    __shared__ _Float16 hs[64][104];
    __shared__ _Float16 wsm[48][104];
    int tid = threadIdx.x;
    int row0 = blockIdx.x * 64;
    int l = tid & 63, w = tid >> 6;
    int l15 = l & 15, lg = l >> 4;

    f32x4 acc[3];
#pragma unroll
    for (int c = 0; c < 3; ++c) acc[c] = (f32x4)0.f;

#pragma unroll
    for (int i = 0; i < 6; ++i) {
        int it = tid + 256 * i;
        int r = it / 24, k4 = it - r * 24;
        int gr = row0 + r;
        h4 hv = {(_Float16)0.f, (_Float16)0.f, (_Float16)0.f, (_Float16)0.f};
        if (gr < n) hv = *(const h4*)&h[(size_t)gr * FH + k4 * 4];
        *(h4*)&hs[r][k4 * 4] = hv;
    }
#pragma unroll
    for (int i = 0; i < 5; ++i) {
        int it = tid + 256 * i;
        if (it < 1152) {
            int r = it / 24, k4 = it - r * 24;
            h4 hv = {(_Float16)0.f, (_Float16)0.f, (_Float16)0.f, (_Float16)0.f};
            if (r < FC) {
                float4 v = *(const float4*)&W2[r * FH + k4 * 4];
                hv[0] = (_Float16)v.x; hv[1] = (_Float16)v.y;
                hv[2] = (_Float16)v.z; hv[3] = (_Float16)v.w;
            }
            *(h4*)&wsm[r][k4 * 4] = hv;
        }
    }
    __syncthreads();
#pragma unroll
    for (int ks = 0; ks < 3; ++ks) {
        h8 a = *(const h8*)&hs[16 * w + l15][ks * 32 + lg * 8];
#pragma unroll
        for (int ct = 0; ct < 3; ++ct) {
            h8 b = *(const h8*)&wsm[ct * 16 + l15][ks * 32 + lg * 8];
            acc[ct] = __builtin_amdgcn_mfma_f32_16x16x32_f16(a, b, acc[ct], 0, 0, 0);
        }
    }
#pragma unroll
    for (int r = 0; r < 4; ++r) {
        int grow = row0 + 16 * w + lg * 4 + r;
        if (grow < n) {
            float dv = dinv[grow];
#pragma unroll
            for (int ct = 0; ct < 3; ++ct) {
                int colc = ct * 16 + l15;
                if (colc < FC)
                    g1h[(size_t)grow * FC + colc] = (_Float16)(dv * acc[ct][r]);
            }
        }
    }
}

// ---------------- aggregation 40 + log_softmax fused (24 nodes/block) ----------------

__global__ __launch_bounds__(256) void k_agg40lsm(const _Float16* __restrict__ g1h,
                                                  const unsigned* __restrict__ off,
                                                  const float2* __restrict__ epk,
                                                  const float* __restrict__ dinv,
                                                  const float* __restrict__ b,
                                                  float* __restrict__ out, int n) {
    __shared__ float sm[24][41];
    int tid = threadIdx.x;
    int ln = tid / 10;
    int f4 = tid - ln * 10;
    int node = blockIdx.x * 24 + ln;
    bool active = (tid < 240) && (node < n);
    float4 acc = make_float4(0.f, 0.f, 0.f, 0.f);
    if (active) {
        h4 self = *(const h4*)&g1h[(size_t)node * FC + f4 * 4];
        acc = make_float4((float)self[0], (float)self[1], (float)self[2], (float)self[3]);
        unsigned st = off[node], en = off[node + 1];
        unsigned e = st;
        for (; e + 4 <= en; e += 4) {
            float2 p0 = epk[e + 0], p1 = epk[e + 1], p2 = epk[e + 2], p3 = epk[e + 3];
            h4 ga = *(const h4*)&g1h[(size_t)__float_as_int(p0.x) * FC + f4 * 4];
            h4 gb = *(const h4*)&g1h[(size_t)__float_as_int(p1.x) * FC + f4 * 4];
            h4 gc = *(const h4*)&g1h[(size_t)__float_as_int(p2.x) * FC + f4 * 4];
            h4 gd = *(const h4*)&g1h[(size_t)__float_as_int(p3.x) * FC + f4 * 4];
            acc.x = fmaf(p0.y, (float)ga[0], acc.x);
            acc.y = fmaf(p0.y, (float)ga[1], acc.y);
            acc.z = fmaf(p0.y, (float)ga[2], acc.z);
            acc.w = fmaf(p0.y, (float)ga[3], acc.w);
            acc.x = fmaf(p1.y, (float)gb[0], acc.x);
            acc.y = fmaf(p1.y, (float)gb[1], acc.y);
            acc.z = fmaf(p1.y, (float)gb[2], acc.z);
            acc.w = fmaf(p1.y, (float)gb[3], acc.w);
            acc.x = fmaf(p2.y, (float)gc[0], acc.x);
            acc.y = fmaf(p2.y, (float)gc[1], acc.y);
            acc.z = fmaf(p2.y, (float)gc[2], acc.z);
            acc.w = fmaf(p2.y, (float)gc[3], acc.w);
            acc.x = fmaf(p3.y, (float)gd[0], acc.x);
            acc.y = fmaf(p3.y, (float)gd[1], acc.y);
            acc.z = fmaf(p3.y, (float)gd[2], acc.z);
            acc.w = fmaf(p3.y, (float)gd[3], acc.w);
        }
        for (; e < en; ++e) {
            float2 p = epk[e];
            h4 g = *(const h4*)&g1h[(size_t)__float_as_int(p.x) * FC + f4 * 4];
            acc.x = fmaf(p.y, (float)g[0], acc.x);
            acc.y = fmaf(p.y, (float)g[1], acc.y);
            acc.z = fmaf(p.y, (float)g[2], acc.z);
            acc.w = fmaf(p.y, (float)g[3], acc.w);
        }
        float s = dinv[node];
        float4 bv = ((const float4*)b)[f4];
        acc.x = fmaf(s, acc.x, bv.x);
        acc.y = fmaf(s, acc.y, bv.y);
        acc.z = fmaf(s, acc.z, bv.z);
        acc.w = fmaf(s, acc.w, bv.w);
        sm[ln][f4 * 4 + 0] = acc.x;
        sm[ln][f4 * 4 + 1] = acc.y;
        sm[ln][f4 * 4 + 2] = acc.z;
        sm[ln][f4 * 4 + 3] = acc.w;
    }
    __syncthreads();
    if (tid < 24) {
        int nd = blockIdx.x * 24 + tid;
        if (nd < n) {
            float m = -INFINITY;
#pragma unroll 8
            for (int j = 0; j < FC; ++j) m = fmaxf(m, sm[tid][j]);
            float sum = 0.f;
#pragma unroll 8
            for (int j = 0; j < FC; ++j) sum += expf(sm[tid][j] - m);
            sm[tid][40] = logf(sum) + m;
        }
    }
    __syncthreads();
    if (active) {
        float lse = sm[ln][40];
        float4 o = make_float4(acc.x - lse, acc.y - lse, acc.z - lse, acc.w - lse);
        *(float4*)&out[(size_t)node * FC + f4 * 4] = o;
    }
}

// ---------------- launch ----------------

extern "C" void kernel_launch(void* const* d_in, const int* in_sizes, int n_in,
                              void* d_out, int out_size, void* d_ws, size_t ws_size,
                              hipStream_t stream) {
    const float* x  = (const float*)d_in[0];
    const int*   ei = (const int*)d_in[1];
    const float* ew = (const float*)d_in[2];
    const float* W1 = (const float*)d_in[3];
    const float* b1 = (const float*)d_in[4];
    const float* W2 = (const float*)d_in[5];
    const float* b2 = (const float*)d_in[6];
    float* out = (float*)d_out;

    const int N = NN;
    const int E = in_sizes[1] / 2;
    const int* row = ei;
    const int* col = ei + E;

    float* ws = (float*)d_ws;
    // workspace layout (4-byte words)
    // overlays of region R = [150976, 4950976):
    //   copies [150976,3350976)                      : k_hist -> k_reduce
    //   bkc [150976,950976), bkrw [950976,2550976)   : k_bucket -> k_place
    //   h   [150976,2550976) (fp16 N*96)             : k_agg96 -> k_gemm2
    // epk  [4950976,6550976): k_place -> k_agg40lsm
    // g0hA [6550976,7750976) (fp16 N*48): k_gemm1 -> k_agg96 pass0
    // g0hB [7750976,8950976) (fp16 N*48): k_gemm1 -> k_agg96 pass1
    // g1h  [8950976,9950976) (fp16 N*40): k_gemm2 -> k_agg40lsm
    float*    dinv   = (float*)(ws + 0);           // N
    unsigned* cnt    = (unsigned*)(ws + 50176);    // N
    unsigned* off    = (unsigned*)(ws + 100352);   // N+1
    unsigned* bsum   = (unsigned*)(ws + 150656);   // 64
    unsigned* gcur   = (unsigned*)(ws + 150720);   // 196 (+pad to 150976)
    unsigned* copies = (unsigned*)(ws + 150976);
    unsigned* bkc    = (unsigned*)(ws + 150976);
    float2*   bkrw   = (float2*)(ws + 950976);
    _Float16* h      = (_Float16*)(ws + 150976);
    float2*   epk    = (float2*)(ws + 4950976);
    _Float16* g0hA   = (_Float16*)(ws + 6550976);
    _Float16* g0hB   = (_Float16*)(ws + 7750976);
    _Float16* g1h    = (_Float16*)(ws + 8950976);

    const int B = 256;
    const int NB_SCAN = (N + 1023) / 1024;

    hipLaunchKernelGGL(k_hist, dim3(256), dim3(B), 0, stream, ei, E, copies);
    hipLaunchKernelGGL(k_reduce, dim3((25000 + B - 1) / B), dim3(B), 0, stream, copies, dinv, cnt);

    hipLaunchKernelGGL(k_scanA, dim3(NB_SCAN), dim3(1024), 0, stream, cnt, off, bsum, N);
    hipLaunchKernelGGL(k_scanB1, dim3(1), dim3(64), 0, stream, bsum, NB_SCAN);
    hipLaunchKernelGGL(k_scanB2, dim3((N + 1 + B - 1) / B), dim3(B), 0, stream, off, bsum, gcur, N, (unsigned)E);

    hipLaunchKernelGGL(k_bucket, dim3(320), dim3(B), 0, stream, row, col, ew, gcur, bkc, bkrw, E);
    hipLaunchKernelGGL(k_place, dim3(NBK), dim3(B), 0, stream, bkc, bkrw, off, epk, N);

    hipLaunchKernelGGL(k_gemm1, dim3((N + 63) / 64), dim3(B), 0, stream, x, W1, dinv, g0hA, g0hB, N);

    hipLaunchKernelGGL(k_agg96, dim3((N * 12 + B - 1) / B), dim3(B), 0, stream,
                       g0hA, off, epk, dinv, b1, h, N);
    hipLaunchKernelGGL(k_agg96, dim3((N * 12 + B - 1) / B), dim3(B), 0, stream,
                       g0hB, off, epk, dinv, b1 + 48, h + 48, N);

    hipLaunchKernelGGL(k_gemm2, dim3((N + 63) / 64), dim3(B), 0, stream, h, W2, dinv, g1h, N);

    hipLaunchKernelGGL(k_agg40lsm, dim3((N + 23) / 24), dim3(B), 0, stream,
                       g1h, off, epk, dinv, b2, out, N);
}

// Round 11
// 144.037 us; speedup vs baseline: 1.1406x; 1.1406x over previous
//
#include <hip/hip_runtime.h>
#include <hip/hip_bf16.h>
#include <hip/hip_fp16.h>
#include <math.h>

#define NN 50000
#define EE 800000
#define FIN 256
#define FH 96
#define FC 40
#define NBK 196   // ceil(50000/256) buckets of 256 nodes

typedef _Float16 h4 __attribute__((ext_vector_type(4)));
typedef _Float16 h8 __attribute__((ext_vector_type(8)));
typedef float f32x4 __attribute__((ext_vector_type(4)));

// ---------------- privatized LDS histogram (deg by row, cnt by col) ----------------

__global__ __launch_bounds__(256) void k_hist(const int* __restrict__ ei, int E,
                                              unsigned* __restrict__ copies) {
    __shared__ unsigned hist[12500];
    int b = blockIdx.x;
    int slice = b & 63;
    int half = (b >> 6) & 1;
    int arr = b >> 7;
    const int* ptr = ei + (size_t)arr * E;  // arr=0: row, arr=1: col
    int tid = threadIdx.x;
    for (int i = tid; i < 12500; i += 256) hist[i] = 0u;
    __syncthreads();
    int ES = (E + 63) >> 6;
    int lo = slice * ES, hi = min(lo + ES, E);
    int nlo = half * 25000;
    for (int i = lo + tid; i < hi; i += 256) {
        int rel = ptr[i] - nlo;
        if ((unsigned)rel < 25000u)
            atomicAdd(&hist[rel >> 1], 1u << ((rel & 1) << 4));
    }
    __syncthreads();
    unsigned* dst = copies + (size_t)((arr * 2 + half) * 64 + slice) * 12500;
    for (int i = tid; i < 12500; i += 256) dst[i] = hist[i];
}

// sum the 64 copies -> dinv (float, rsqrt(deg+1)) and cnt (u32)
__global__ void k_reduce(const unsigned* __restrict__ copies,
                         float* __restrict__ dinv, unsigned* __restrict__ cnt) {
    int t = blockIdx.x * blockDim.x + threadIdx.x;  // 0..24999
    if (t >= 25000) return;
    int half = t / 12500, w = t - half * 12500;
    unsigned sr = 0, sc = 0;
    const unsigned* br = copies + (size_t)(half) * 64 * 12500 + w;      // rows
    const unsigned* bc = copies + (size_t)(2 + half) * 64 * 12500 + w;  // cols
#pragma unroll 8
    for (int s = 0; s < 64; ++s) { sr += br[s * 12500]; sc += bc[s * 12500]; }
    int n0 = half * 25000 + 2 * w;
    dinv[n0]     = rsqrtf((float)((sr & 0xffffu) + 1u));
    dinv[n0 + 1] = rsqrtf((float)((sr >> 16) + 1u));
    cnt[n0]     = sc & 0xffffu;
    cnt[n0 + 1] = sc >> 16;
}

// ---------------- exclusive scan of cnt -> off ----------------

__global__ __launch_bounds__(1024) void k_scanA(const unsigned* __restrict__ cnt,
                                                unsigned* __restrict__ off,
                                                unsigned* __restrict__ bsum, int n) {
    __shared__ unsigned s[1024];
    int t = threadIdx.x;
    int i = blockIdx.x * 1024 + t;
    unsigned v = (i < n) ? cnt[i] : 0u;
    s[t] = v;
    __syncthreads();
    for (int o = 1; o < 1024; o <<= 1) {
        unsigned tv = (t >= o) ? s[t - o] : 0u;
        __syncthreads();
        s[t] += tv;
        __syncthreads();
    }
    if (i < n) off[i] = s[t] - v;  // exclusive
    if (t == 1023) bsum[blockIdx.x] = s[1023];
}

__global__ void k_scanB1(unsigned* bsum, int nb) {
    if (threadIdx.x == 0 && blockIdx.x == 0) {
        unsigned run = 0;
        for (int b = 0; b < nb; ++b) { unsigned tv = bsum[b]; bsum[b] = run; run += tv; }
    }
}

// adds block prefix; also initializes gcur[b] = off[b*256]
__global__ void k_scanB2(unsigned* __restrict__ off, const unsigned* __restrict__ bsum,
                         unsigned* __restrict__ gcur, int n, unsigned e) {
    int i = blockIdx.x * blockDim.x + threadIdx.x;
    if (i < n) {
        unsigned v = off[i] + bsum[i >> 10];
        off[i] = v;
        if ((i & 255) == 0) gcur[i >> 8] = v;
    }
    if (i == n) off[n] = e;
}

// ---------------- P1: coarse bucket by col>>8 ----------------

__global__ __launch_bounds__(256) void k_bucket(const int* __restrict__ row,
                                                const int* __restrict__ col,
                                                const float* __restrict__ ew,
                                                unsigned* __restrict__ gcur,
                                                unsigned* __restrict__ bkc,
                                                float2* __restrict__ bkrw, int E) {
    __shared__ unsigned cnt[NBK];
    __shared__ unsigned cur[NBK];
    int tid = threadIdx.x;
    int CH = (E + gridDim.x - 1) / gridDim.x;
    int lo = blockIdx.x * CH, hi = min(lo + CH, E);
    for (int i = tid; i < NBK; i += 256) cnt[i] = 0u;
    __syncthreads();
    for (int i = lo + tid; i < hi; i += 256) atomicAdd(&cnt[col[i] >> 8], 1u);
    __syncthreads();
    for (int i = tid; i < NBK; i += 256) cur[i] = atomicAdd(&gcur[i], cnt[i]);
    __syncthreads();
    for (int i = lo + tid; i < hi; i += 256) {
        int c = col[i];
        unsigned pos = atomicAdd(&cur[c >> 8], 1u);
        bkc[pos] = (unsigned)c;
        float2 p;
        p.x = __int_as_float(row[i]);
        p.y = ew[i];
        bkrw[pos] = p;
    }
}

// ---------------- P2: exact place within bucket ----------------

__global__ __launch_bounds__(256) void k_place(const unsigned* __restrict__ bkc,
                                               const float2* __restrict__ bkrw,
                                               const unsigned* __restrict__ off,
                                               float2* __restrict__ epk, int n) {
    __shared__ unsigned cur[256];
    int b = blockIdx.x;
    int tid = threadIdx.x;
    int node0 = b * 256;
    int node = node0 + tid;
    cur[tid] = off[(node <= n) ? node : n];
    __syncthreads();
    unsigned st = off[node0];
    unsigned en = off[min(node0 + 256, n)];
    for (unsigned i = st + tid; i < en; i += 256) {
        unsigned c = bkc[i];
        unsigned pos = atomicAdd(&cur[c & 255], 1u);
        epk[pos] = bkrw[i];
    }
}

// ---------------- GEMM1 (MFMA fp16): g0h = fp16( dinv ⊙ (x @ W1^T) ), interleaved N x 96 ----------------

__global__ __launch_bounds__(256) void k_gemm1(const float* __restrict__ x,
                                               const float* __restrict__ W,
                                               const float* __restrict__ dinv,
                                               _Float16* __restrict__ g0h, int n) {
    __shared__ _Float16 xs[64][72];
    __shared__ _Float16 wsm[96][72];
    int tid = threadIdx.x;
    int row0 = blockIdx.x * 64;
    int l = tid & 63, w = tid >> 6;
    int l15 = l & 15, lg = l >> 4;

    f32x4 acc[6];
#pragma unroll
    for (int c = 0; c < 6; ++c) acc[c] = (f32x4)0.f;

    for (int kc = 0; kc < 4; ++kc) {
        int kbase = kc * 64;
#pragma unroll
        for (int i = 0; i < 4; ++i) {
            int it = tid + 256 * i;
            int r = it >> 4, k4 = it & 15;
            float4 v = make_float4(0.f, 0.f, 0.f, 0.f);
            int gr = row0 + r;
            if (gr < n) v = *(const float4*)&x[gr * FIN + kbase + k4 * 4];
            h4 hv = {(_Float16)v.x, (_Float16)v.y, (_Float16)v.z, (_Float16)v.w};
            *(h4*)&xs[r][k4 * 4] = hv;
        }
#pragma unroll
        for (int i = 0; i < 6; ++i) {
            int it = tid + 256 * i;
            int r = it >> 4, k4 = it & 15;
            float4 v = *(const float4*)&W[r * FIN + kbase + k4 * 4];
            h4 hv = {(_Float16)v.x, (_Float16)v.y, (_Float16)v.z, (_Float16)v.w};
            *(h4*)&wsm[r][k4 * 4] = hv;
        }
        __syncthreads();
#pragma unroll
        for (int ks = 0; ks < 2; ++ks) {
            h8 a = *(const h8*)&xs[16 * w + l15][ks * 32 + lg * 8];
#pragma unroll
            for (int ct = 0; ct < 6; ++ct) {
                h8 b = *(const h8*)&wsm[ct * 16 + l15][ks * 32 + lg * 8];
                acc[ct] = __builtin_amdgcn_mfma_f32_16x16x32_f16(a, b, acc[ct], 0, 0, 0);
            }
        }
        __syncthreads();
    }
#pragma unroll
    for (int r = 0; r < 4; ++r) {
        int grow = row0 + 16 * w + lg * 4 + r;
        if (grow < n) {
            float dv = dinv[grow];
#pragma unroll
            for (int ct = 0; ct < 6; ++ct)
                g0h[(size_t)grow * FH + ct * 16 + l15] = (_Float16)(dv * acc[ct][r]);
        }
    }
}

// ---------------- aggregation 96: 12 threads/node, h8 (16B) gathers, unroll-4 ----------------

__global__ __launch_bounds__(256) void k_agg96(const _Float16* __restrict__ g0h,
                                               const unsigned* __restrict__ off,
                                               const float2* __restrict__ epk,
                                               const float* __restrict__ dinv,
                                               const float* __restrict__ b,
                                               _Float16* __restrict__ outh, int n) {
    int tid = blockIdx.x * 256 + threadIdx.x;
    int node = tid / 12;
    int f8 = tid - node * 12;
    if (node >= n) return;
    const h8* gp = (const h8*)g0h;  // row = 12 h8 chunks
    h8 self = gp[(size_t)node * 12 + f8];
    float acc[8];
#pragma unroll
    for (int j = 0; j < 8; ++j) acc[j] = (float)self[j];
    unsigned st = off[node], en = off[node + 1];
    unsigned e = st;
    for (; e + 4 <= en; e += 4) {
        float2 p0 = epk[e + 0], p1 = epk[e + 1], p2 = epk[e + 2], p3 = epk[e + 3];
        h8 ga = gp[(size_t)__float_as_int(p0.x) * 12 + f8];
        h8 gb = gp[(size_t)__float_as_int(p1.x) * 12 + f8];
        h8 gc = gp[(size_t)__float_as_int(p2.x) * 12 + f8];
        h8 gd = gp[(size_t)__float_as_int(p3.x) * 12 + f8];
#pragma unroll
        for (int j = 0; j < 8; ++j) acc[j] = fmaf(p0.y, (float)ga[j], acc[j]);
#pragma unroll
        for (int j = 0; j < 8; ++j) acc[j] = fmaf(p1.y, (float)gb[j], acc[j]);
#pragma unroll
        for (int j = 0; j < 8; ++j) acc[j] = fmaf(p2.y, (float)gc[j], acc[j]);
#pragma unroll
        for (int j = 0; j < 8; ++j) acc[j] = fmaf(p3.y, (float)gd[j], acc[j]);
    }
    for (; e < en; ++e) {
        float2 p = epk[e];
        h8 g = gp[(size_t)__float_as_int(p.x) * 12 + f8];
#pragma unroll
        for (int j = 0; j < 8; ++j) acc[j] = fmaf(p.y, (float)g[j], acc[j]);
    }
    float s = dinv[node];
    float4 bv0 = ((const float4*)b)[f8 * 2];
    float4 bv1 = ((const float4*)b)[f8 * 2 + 1];
    const float bb[8] = {bv0.x, bv0.y, bv0.z, bv0.w, bv1.x, bv1.y, bv1.z, bv1.w};
    h8 o;
#pragma unroll
    for (int j = 0; j < 8; ++j) o[j] = (_Float16)fmaxf(fmaf(s, acc[j], bb[j]), 0.f);
    *(h8*)&outh[(size_t)node * FH + f8 * 8] = o;
}

// ---------------- GEMM2 (MFMA fp16): g1h = fp16( dinv ⊙ (h @ W2^T) ) ----------------

__global__ __launch_bounds__(256) void k_gemm2(const _Float16* __restrict__ h,
                                               const float* __restrict__ W2,
                                               const float* __restrict__ dinv,
                                               _Float16* __restrict__ g1h, int n) {
    __shared__ _Float16 hs[64][104];
    __shared__ _Float16 wsm[48][104];
    int tid = threadIdx.x;
    int row0 = blockIdx.x * 64;
    int l = tid & 63, w = tid >> 6;
    int l15 = l & 15, lg = l >> 4;

    f32x4 acc[3];
#pragma unroll
    for (int c = 0; c < 3; ++c) acc[c] = (f32x4)0.f;

#pragma unroll
    for (int i = 0; i < 6; ++i) {
        int it = tid + 256 * i;
        int r = it / 24, k4 = it - r * 24;
        int gr = row0 + r;
        h4 hv = {(_Float16)0.f, (_Float16)0.f, (_Float16)0.f, (_Float16)0.f};
        if (gr < n) hv = *(const h4*)&h[(size_t)gr * FH + k4 * 4];
        *(h4*)&hs[r][k4 * 4] = hv;
    }
#pragma unroll
    for (int i = 0; i < 5; ++i) {
        int it = tid + 256 * i;
        if (it < 1152) {
            int r = it / 24, k4 = it - r * 24;
            h4 hv = {(_Float16)0.f, (_Float16)0.f, (_Float16)0.f, (_Float16)0.f};
            if (r < FC) {
                float4 v = *(const float4*)&W2[r * FH + k4 * 4];
                hv[0] = (_Float16)v.x; hv[1] = (_Float16)v.y;
                hv[2] = (_Float16)v.z; hv[3] = (_Float16)v.w;
            }
            *(h4*)&wsm[r][k4 * 4] = hv;
        }
    }
    __syncthreads();
#pragma unroll
    for (int ks = 0; ks < 3; ++ks) {
        h8 a = *(const h8*)&hs[16 * w + l15][ks * 32 + lg * 8];
#pragma unroll
        for (int ct = 0; ct < 3; ++ct) {
            h8 b = *(const h8*)&wsm[ct * 16 + l15][ks * 32 + lg * 8];
            acc[ct] = __builtin_amdgcn_mfma_f32_16x16x32_f16(a, b, acc[ct], 0, 0, 0);
        }
    }
#pragma unroll
    for (int r = 0; r < 4; ++r) {
        int grow = row0 + 16 * w + lg * 4 + r;
        if (grow < n) {
            float dv = dinv[grow];
#pragma unroll
            for (int ct = 0; ct < 3; ++ct) {
                int colc = ct * 16 + l15;
                if (colc < FC)
                    g1h[(size_t)grow * FC + colc] = (_Float16)(dv * acc[ct][r]);
            }
        }
    }
}

// ---------------- aggregation 40 + log_softmax fused: 5 threads/node h8, 50 nodes/block ----------------

__global__ __launch_bounds__(256) void k_agg40lsm(const _Float16* __restrict__ g1h,
                                                  const unsigned* __restrict__ off,
                                                  const float2* __restrict__ epk,
                                                  const float* __restrict__ dinv,
                                                  const float* __restrict__ b,
                                                  float* __restrict__ out, int n) {
    __shared__ float sm[50][41];
    int tid = threadIdx.x;
    int ln = tid / 5;
    int f8 = tid - ln * 5;
    int node = blockIdx.x * 50 + ln;
    bool active = (tid < 250) && (node < n);
    float acc[8];
#pragma unroll
    for (int j = 0; j < 8; ++j) acc[j] = 0.f;
    if (active) {
        const h8* gp = (const h8*)g1h;  // row = 5 h8 chunks
        h8 self = gp[(size_t)node * 5 + f8];
#pragma unroll
        for (int j = 0; j < 8; ++j) acc[j] = (float)self[j];
        unsigned st = off[node], en = off[node + 1];
        unsigned e = st;
        for (; e + 4 <= en; e += 4) {
            float2 p0 = epk[e + 0], p1 = epk[e + 1], p2 = epk[e + 2], p3 = epk[e + 3];
            h8 ga = gp[(size_t)__float_as_int(p0.x) * 5 + f8];
            h8 gb = gp[(size_t)__float_as_int(p1.x) * 5 + f8];
            h8 gc = gp[(size_t)__float_as_int(p2.x) * 5 + f8];
            h8 gd = gp[(size_t)__float_as_int(p3.x) * 5 + f8];
#pragma unroll
            for (int j = 0; j < 8; ++j) acc[j] = fmaf(p0.y, (float)ga[j], acc[j]);
#pragma unroll
            for (int j = 0; j < 8; ++j) acc[j] = fmaf(p1.y, (float)gb[j], acc[j]);
#pragma unroll
            for (int j = 0; j < 8; ++j) acc[j] = fmaf(p2.y, (float)gc[j], acc[j]);
#pragma unroll
            for (int j = 0; j < 8; ++j) acc[j] = fmaf(p3.y, (float)gd[j], acc[j]);
        }
        for (; e < en; ++e) {
            float2 p = epk[e];
            h8 g = gp[(size_t)__float_as_int(p.x) * 5 + f8];
#pragma unroll
            for (int j = 0; j < 8; ++j) acc[j] = fmaf(p.y, (float)g[j], acc[j]);
        }
        float s = dinv[node];
        float4 bv0 = ((const float4*)b)[f8 * 2];
        float4 bv1 = ((const float4*)b)[f8 * 2 + 1];
        const float bb[8] = {bv0.x, bv0.y, bv0.z, bv0.w, bv1.x, bv1.y, bv1.z, bv1.w};
#pragma unroll
        for (int j = 0; j < 8; ++j) {
            acc[j] = fmaf(s, acc[j], bb[j]);
            sm[ln][f8 * 8 + j] = acc[j];
        }
    }
    __syncthreads();
    if (tid < 50) {
        int nd = blockIdx.x * 50 + tid;
        if (nd < n) {
            float m = -INFINITY;
#pragma unroll 8
            for (int j = 0; j < FC; ++j) m = fmaxf(m, sm[tid][j]);
            float sum = 0.f;
#pragma unroll 8
            for (int j = 0; j < FC; ++j) sum += expf(sm[tid][j] - m);
            sm[tid][40] = logf(sum) + m;
        }
    }
    __syncthreads();
    if (active) {
        float lse = sm[ln][40];
        float4 o0 = make_float4(acc[0] - lse, acc[1] - lse, acc[2] - lse, acc[3] - lse);
        float4 o1 = make_float4(acc[4] - lse, acc[5] - lse, acc[6] - lse, acc[7] - lse);
        *(float4*)&out[(size_t)node * FC + f8 * 8] = o0;
        *(float4*)&out[(size_t)node * FC + f8 * 8 + 4] = o1;
    }
}

// ---------------- launch ----------------

extern "C" void kernel_launch(void* const* d_in, const int* in_sizes, int n_in,
                              void* d_out, int out_size, void* d_ws, size_t ws_size,
                              hipStream_t stream) {
    const float* x  = (const float*)d_in[0];
    const int*   ei = (const int*)d_in[1];
    const float* ew = (const float*)d_in[2];
    const float* W1 = (const float*)d_in[3];
    const float* b1 = (const float*)d_in[4];
    const float* W2 = (const float*)d_in[5];
    const float* b2 = (const float*)d_in[6];
    float* out = (float*)d_out;

    const int N = NN;
    const int E = in_sizes[1] / 2;
    const int* row = ei;
    const int* col = ei + E;

    float* ws = (float*)d_ws;
    // workspace layout (4-byte words); total 9,950,976 words = 39.8 MB
    // overlays of region R = [150976, 4950976):
    //   copies [150976,3350976)                      : k_hist -> k_reduce
    //   bkc [150976,950976), bkrw [950976,2550976)   : k_bucket -> k_place
    //   h   [150976,2550976) (fp16 N*96)             : k_agg96 -> k_gemm2
    // epk [4950976,6550976): k_place -> k_agg40lsm
    // g0h [6550976,8950976) (fp16 N*96): k_gemm1 -> k_agg96
    // g1h [8950976,9950976) (fp16 N*40): k_gemm2 -> k_agg40lsm
    float*    dinv   = (float*)(ws + 0);           // N
    unsigned* cnt    = (unsigned*)(ws + 50176);    // N
    unsigned* off    = (unsigned*)(ws + 100352);   // N+1
    unsigned* bsum   = (unsigned*)(ws + 150656);   // 64
    unsigned* gcur   = (unsigned*)(ws + 150720);   // 196 (+pad to 150976)
    unsigned* copies = (unsigned*)(ws + 150976);
    unsigned* bkc    = (unsigned*)(ws + 150976);
    float2*   bkrw   = (float2*)(ws + 950976);
    _Float16* h      = (_Float16*)(ws + 150976);
    float2*   epk    = (float2*)(ws + 4950976);
    _Float16* g0h    = (_Float16*)(ws + 6550976);
    _Float16* g1h    = (_Float16*)(ws + 8950976);

    const int B = 256;
    const int NB_SCAN = (N + 1023) / 1024;

    hipLaunchKernelGGL(k_hist, dim3(256), dim3(B), 0, stream, ei, E, copies);
    hipLaunchKernelGGL(k_reduce, dim3((25000 + B - 1) / B), dim3(B), 0, stream, copies, dinv, cnt);

    hipLaunchKernelGGL(k_scanA, dim3(NB_SCAN), dim3(1024), 0, stream, cnt, off, bsum, N);
    hipLaunchKernelGGL(k_scanB1, dim3(1), dim3(64), 0, stream, bsum, NB_SCAN);
    hipLaunchKernelGGL(k_scanB2, dim3((N + 1 + B - 1) / B), dim3(B), 0, stream, off, bsum, gcur, N, (unsigned)E);

    hipLaunchKernelGGL(k_bucket, dim3(320), dim3(B), 0, stream, row, col, ew, gcur, bkc, bkrw, E);
    hipLaunchKernelGGL(k_place, dim3(NBK), dim3(B), 0, stream, bkc, bkrw, off, epk, N);

    hipLaunchKernelGGL(k_gemm1, dim3((N + 63) / 64), dim3(B), 0, stream, x, W1, dinv, g0h, N);

    hipLaunchKernelGGL(k_agg96, dim3((N * 12 + B - 1) / B), dim3(B), 0, stream,
                       g0h, off, epk, dinv, b1, h, N);

    hipLaunchKernelGGL(k_gemm2, dim3((N + 63) / 64), dim3(B), 0, stream, h, W2, dinv, g1h, N);

    hipLaunchKernelGGL(k_agg40lsm, dim3((N + 49) / 50), dim3(B), 0, stream,
                       g1h, off, epk, dinv, b2, out, N);
}

// Round 12
// 142.190 us; speedup vs baseline: 1.1554x; 1.0130x over previous
//
#include <hip/hip_runtime.h>
#include <hip/hip_bf16.h>
#include <hip/hip_fp16.h>
#include <math.h>

#define NN 50000
#define EE 800000
#define FIN 256
#define FH 96
#define FC 40
#define NBK 196   // ceil(50000/256) buckets of 256 nodes

typedef _Float16 h4 __attribute__((ext_vector_type(4)));
typedef _Float16 h8 __attribute__((ext_vector_type(8)));
typedef float f32x4 __attribute__((ext_vector_type(4)));

// ---------------- fused: row-degree LDS histogram (blocks 0-127) + col bucket-count (blocks 128-191) ----------------

__global__ __launch_bounds__(256) void k_histcnt(const int* __restrict__ ei, int E,
                                                 unsigned* __restrict__ copies,
                                                 unsigned* __restrict__ bcnt) {
    __shared__ unsigned lds[12500];
    int b = blockIdx.x;
    int tid = threadIdx.x;
    int ES = (E + 63) >> 6;
    if (b < 128) {
        // row-degree histogram, 16-bit packed, half of node range per blockset
        int slice = b & 63, half = b >> 6;
        const int* ptr = ei;  // row
        for (int i = tid; i < 12500; i += 256) lds[i] = 0u;
        __syncthreads();
        int lo = slice * ES, hi = min(lo + ES, E);
        int nlo = half * 25000;
        for (int i = lo + tid; i < hi; i += 256) {
            int rel = ptr[i] - nlo;
            if ((unsigned)rel < 25000u)
                atomicAdd(&lds[rel >> 1], 1u << ((rel & 1) << 4));
        }
        __syncthreads();
        unsigned* dst = copies + (size_t)(half * 64 + slice) * 12500;
        for (int i = tid; i < 12500; i += 256) dst[i] = lds[i];
    } else {
        // per-bucket (col>>8) counts, 64 chunks
        int chunk = b - 128;
        const int* col = ei + E;
        for (int i = tid; i < NBK; i += 256) lds[i] = 0u;
        __syncthreads();
        int lo = chunk * ES, hi = min(lo + ES, E);
        for (int i = lo + tid; i < hi; i += 256) atomicAdd(&lds[col[i] >> 8], 1u);
        __syncthreads();
        for (int i = tid; i < NBK; i += 256)
            if (lds[i]) atomicAdd(&bcnt[i], lds[i]);
    }
}

// ---------------- reduce row-copies -> dinv; block 0 also scans bcnt -> bstart/gcur ----------------

__global__ __launch_bounds__(256) void k_reduce(const unsigned* __restrict__ copies,
                                                const unsigned* __restrict__ bcnt,
                                                float* __restrict__ dinv,
                                                unsigned* __restrict__ bstart,
                                                unsigned* __restrict__ gcur,
                                                unsigned* __restrict__ off, unsigned E) {
    int t = blockIdx.x * blockDim.x + threadIdx.x;  // 0..24999
    if (t < 25000) {
        int half = t / 12500, w = t - half * 12500;
        unsigned sr = 0;
        const unsigned* br = copies + (size_t)half * 64 * 12500 + w;
#pragma unroll 8
        for (int s = 0; s < 64; ++s) sr += br[s * 12500];
        int n0 = half * 25000 + 2 * w;
        dinv[n0]     = rsqrtf((float)((sr & 0xffffu) + 1u));
        dinv[n0 + 1] = rsqrtf((float)((sr >> 16) + 1u));
    }
    if (blockIdx.x == 0) {
        __shared__ unsigned sb[256];
        int tt = threadIdx.x;
        unsigned v = (tt < NBK) ? bcnt[tt] : 0u;
        sb[tt] = v;
        __syncthreads();
        for (int o = 1; o < 256; o <<= 1) {
            unsigned tv = (tt >= o) ? sb[tt - o] : 0u;
            __syncthreads();
            sb[tt] += tv;
            __syncthreads();
        }
        if (tt < NBK) {
            unsigned ex = sb[tt] - v;     // exclusive
            bstart[tt] = ex;
            gcur[tt] = ex;
            bstart[tt + 1] = sb[tt];      // inclusive -> next bucket start (tt=195 -> E)
        }
        if (tt == 0) off[NN] = E;
    }
}

// ---------------- P1: coarse bucket by col>>8 (count, reserve, place) ----------------

__global__ __launch_bounds__(256) void k_bucket(const int* __restrict__ row,
                                                const int* __restrict__ col,
                                                const float* __restrict__ ew,
                                                unsigned* __restrict__ gcur,
                                                unsigned* __restrict__ bkc,
                                                float2* __restrict__ bkrw, int E) {
    __shared__ unsigned cnt[NBK];
    __shared__ unsigned cur[NBK];
    int tid = threadIdx.x;
    int CH = (E + gridDim.x - 1) / gridDim.x;
    int lo = blockIdx.x * CH, hi = min(lo + CH, E);
    for (int i = tid; i < NBK; i += 256) cnt[i] = 0u;
    __syncthreads();
    for (int i = lo + tid; i < hi; i += 256) atomicAdd(&cnt[col[i] >> 8], 1u);
    __syncthreads();
    for (int i = tid; i < NBK; i += 256) cur[i] = atomicAdd(&gcur[i], cnt[i]);
    __syncthreads();
    for (int i = lo + tid; i < hi; i += 256) {
        int c = col[i];
        unsigned pos = atomicAdd(&cur[c >> 8], 1u);
        bkc[pos] = (unsigned)c;
        float2 p;
        p.x = __int_as_float(row[i]);
        p.y = ew[i];
        bkrw[pos] = p;
    }
}

// ---------------- P2: per-bucket count + scan -> off[], then exact place ----------------

__global__ __launch_bounds__(256) void k_place(const unsigned* __restrict__ bkc,
                                               const float2* __restrict__ bkrw,
                                               const unsigned* __restrict__ bstart,
                                               unsigned* __restrict__ off,
                                               float2* __restrict__ epk, int n) {
    __shared__ unsigned cnt[256];
    __shared__ unsigned cur[256];
    int b = blockIdx.x;
    int tid = threadIdx.x;
    int node0 = b * 256;
    unsigned st = bstart[b], en = bstart[b + 1];
    cnt[tid] = 0u;
    __syncthreads();
    for (unsigned i = st + tid; i < en; i += 256) atomicAdd(&cnt[bkc[i] & 255], 1u);
    __syncthreads();
    unsigned v = cnt[tid];
    cur[tid] = v;
    __syncthreads();
    for (int o = 1; o < 256; o <<= 1) {
        unsigned tv = (tid >= o) ? cur[tid - o] : 0u;
        __syncthreads();
        cur[tid] += tv;
        __syncthreads();
    }
    unsigned base = st + cur[tid] - v;  // exclusive prefix + bucket start
    int node = node0 + tid;
    if (node < n) off[node] = base;
    cur[tid] = base;
    __syncthreads();
    for (unsigned i = st + tid; i < en; i += 256) {
        unsigned c = bkc[i];
        unsigned pos = atomicAdd(&cur[c & 255], 1u);
        epk[pos] = bkrw[i];
    }
}

// ---------------- GEMM1 (MFMA fp16): g0h = fp16( dinv ⊙ (x @ W1^T) ), interleaved N x 96 ----------------

__global__ __launch_bounds__(256) void k_gemm1(const float* __restrict__ x,
                                               const float* __restrict__ W,
                                               const float* __restrict__ dinv,
                                               _Float16* __restrict__ g0h, int n) {
    __shared__ _Float16 xs[64][72];
    __shared__ _Float16 wsm[96][72];
    int tid = threadIdx.x;
    int row0 = blockIdx.x * 64;
    int l = tid & 63, w = tid >> 6;
    int l15 = l & 15, lg = l >> 4;

    f32x4 acc[6];
#pragma unroll
    for (int c = 0; c < 6; ++c) acc[c] = (f32x4)0.f;

    for (int kc = 0; kc < 4; ++kc) {
        int kbase = kc * 64;
#pragma unroll
        for (int i = 0; i < 4; ++i) {
            int it = tid + 256 * i;
            int r = it >> 4, k4 = it & 15;
            float4 v = make_float4(0.f, 0.f, 0.f, 0.f);
            int gr = row0 + r;
            if (gr < n) v = *(const float4*)&x[gr * FIN + kbase + k4 * 4];
            h4 hv = {(_Float16)v.x, (_Float16)v.y, (_Float16)v.z, (_Float16)v.w};
            *(h4*)&xs[r][k4 * 4] = hv;
        }
#pragma unroll
        for (int i = 0; i < 6; ++i) {
            int it = tid + 256 * i;
            int r = it >> 4, k4 = it & 15;
            float4 v = *(const float4*)&W[r * FIN + kbase + k4 * 4];
            h4 hv = {(_Float16)v.x, (_Float16)v.y, (_Float16)v.z, (_Float16)v.w};
            *(h4*)&wsm[r][k4 * 4] = hv;
        }
        __syncthreads();
#pragma unroll
        for (int ks = 0; ks < 2; ++ks) {
            h8 a = *(const h8*)&xs[16 * w + l15][ks * 32 + lg * 8];
#pragma unroll
            for (int ct = 0; ct < 6; ++ct) {
                h8 b = *(const h8*)&wsm[ct * 16 + l15][ks * 32 + lg * 8];
                acc[ct] = __builtin_amdgcn_mfma_f32_16x16x32_f16(a, b, acc[ct], 0, 0, 0);
            }
        }
        __syncthreads();
    }
#pragma unroll
    for (int r = 0; r < 4; ++r) {
        int grow = row0 + 16 * w + lg * 4 + r;
        if (grow < n) {
            float dv = dinv[grow];
#pragma unroll
            for (int ct = 0; ct < 6; ++ct)
                g0h[(size_t)grow * FH + ct * 16 + l15] = (_Float16)(dv * acc[ct][r]);
        }
    }
}

// ---------------- aggregation 96: 12 threads/node, h8 (16B) gathers, unroll-4 ----------------

__global__ __launch_bounds__(256) void k_agg96(const _Float16* __restrict__ g0h,
                                               const unsigned* __restrict__ off,
                                               const float2* __restrict__ epk,
                                               const float* __restrict__ dinv,
                                               const float* __restrict__ b,
                                               _Float16* __restrict__ outh, int n) {
    int tid = blockIdx.x * 256 + threadIdx.x;
    int node = tid / 12;
    int f8 = tid - node * 12;
    if (node >= n) return;
    const h8* gp = (const h8*)g0h;  // row = 12 h8 chunks
    h8 self = gp[(size_t)node * 12 + f8];
    float acc[8];
#pragma unroll
    for (int j = 0; j < 8; ++j) acc[j] = (float)self[j];
    unsigned st = off[node], en = off[node + 1];
    unsigned e = st;
    for (; e + 4 <= en; e += 4) {
        float2 p0 = epk[e + 0], p1 = epk[e + 1], p2 = epk[e + 2], p3 = epk[e + 3];
        h8 ga = gp[(size_t)__float_as_int(p0.x) * 12 + f8];
        h8 gb = gp[(size_t)__float_as_int(p1.x) * 12 + f8];
        h8 gc = gp[(size_t)__float_as_int(p2.x) * 12 + f8];
        h8 gd = gp[(size_t)__float_as_int(p3.x) * 12 + f8];
#pragma unroll
        for (int j = 0; j < 8; ++j) acc[j] = fmaf(p0.y, (float)ga[j], acc[j]);
#pragma unroll
        for (int j = 0; j < 8; ++j) acc[j] = fmaf(p1.y, (float)gb[j], acc[j]);
#pragma unroll
        for (int j = 0; j < 8; ++j) acc[j] = fmaf(p2.y, (float)gc[j], acc[j]);
#pragma unroll
        for (int j = 0; j < 8; ++j) acc[j] = fmaf(p3.y, (float)gd[j], acc[j]);
    }
    for (; e < en; ++e) {
        float2 p = epk[e];
        h8 g = gp[(size_t)__float_as_int(p.x) * 12 + f8];
#pragma unroll
        for (int j = 0; j < 8; ++j) acc[j] = fmaf(p.y, (float)g[j], acc[j]);
    }
    float s = dinv[node];
    float4 bv0 = ((const float4*)b)[f8 * 2];
    float4 bv1 = ((const float4*)b)[f8 * 2 + 1];
    const float bb[8] = {bv0.x, bv0.y, bv0.z, bv0.w, bv1.x, bv1.y, bv1.z, bv1.w};
    h8 o;
#pragma unroll
    for (int j = 0; j < 8; ++j) o[j] = (_Float16)fmaxf(fmaf(s, acc[j], bb[j]), 0.f);
    *(h8*)&outh[(size_t)node * FH + f8 * 8] = o;
}

// ---------------- GEMM2 (MFMA fp16): g1h = fp16( dinv ⊙ (h @ W2^T) ) ----------------

__global__ __launch_bounds__(256) void k_gemm2(const _Float16* __restrict__ h,
                                               const float* __restrict__ W2,
                                               const float* __restrict__ dinv,
                                               _Float16* __restrict__ g1h, int n) {
    __shared__ _Float16 hs[64][104];
    __shared__ _Float16 wsm[48][104];
    int tid = threadIdx.x;
    int row0 = blockIdx.x * 64;
    int l = tid & 63, w = tid >> 6;
    int l15 = l & 15, lg = l >> 4;

    f32x4 acc[3];
#pragma unroll
    for (int c = 0; c < 3; ++c) acc[c] = (f32x4)0.f;

#pragma unroll
    for (int i = 0; i < 6; ++i) {
        int it = tid + 256 * i;
        int r = it / 24, k4 = it - r * 24;
        int gr = row0 + r;
        h4 hv = {(_Float16)0.f, (_Float16)0.f, (_Float16)0.f, (_Float16)0.f};
        if (gr < n) hv = *(const h4*)&h[(size_t)gr * FH + k4 * 4];
        *(h4*)&hs[r][k4 * 4] = hv;
    }
#pragma unroll
    for (int i = 0; i < 5; ++i) {
        int it = tid + 256 * i;
        if (it < 1152) {
            int r = it / 24, k4 = it - r * 24;
            h4 hv = {(_Float16)0.f, (_Float16)0.f, (_Float16)0.f, (_Float16)0.f};
            if (r < FC) {
                float4 v = *(const float4*)&W2[r * FH + k4 * 4];
                hv[0] = (_Float16)v.x; hv[1] = (_Float16)v.y;
                hv[2] = (_Float16)v.z; hv[3] = (_Float16)v.w;
            }
            *(h4*)&wsm[r][k4 * 4] = hv;
        }
    }
    __syncthreads();
#pragma unroll
    for (int ks = 0; ks < 3; ++ks) {
        h8 a = *(const h8*)&hs[16 * w + l15][ks * 32 + lg * 8];
#pragma unroll
        for (int ct = 0; ct < 3; ++ct) {
            h8 b = *(const h8*)&wsm[ct * 16 + l15][ks * 32 + lg * 8];
            acc[ct] = __builtin_amdgcn_mfma_f32_16x16x32_f16(a, b, acc[ct], 0, 0, 0);
        }
    }
#pragma unroll
    for (int r = 0; r < 4; ++r) {
        int grow = row0 + 16 * w + lg * 4 + r;
        if (grow < n) {
            float dv = dinv[grow];
#pragma unroll
            for (int ct = 0; ct < 3; ++ct) {
                int colc = ct * 16 + l15;
                if (colc < FC)
                    g1h[(size_t)grow * FC + colc] = (_Float16)(dv * acc[ct][r]);
            }
        }
    }
}

// ---------------- aggregation 40 + log_softmax fused: 5 threads/node h8, 50 nodes/block ----------------

__global__ __launch_bounds__(256) void k_agg40lsm(const _Float16* __restrict__ g1h,
                                                  const unsigned* __restrict__ off,
                                                  const float2* __restrict__ epk,
                                                  const float* __restrict__ dinv,
                                                  const float* __restrict__ b,
                                                  float* __restrict__ out, int n) {
    __shared__ float sm[50][41];
    int tid = threadIdx.x;
    int ln = tid / 5;
    int f8 = tid - ln * 5;
    int node = blockIdx.x * 50 + ln;
    bool active = (tid < 250) && (node < n);
    float acc[8];
#pragma unroll
    for (int j = 0; j < 8; ++j) acc[j] = 0.f;
    if (active) {
        const h8* gp = (const h8*)g1h;  // row = 5 h8 chunks
        h8 self = gp[(size_t)node * 5 + f8];
#pragma unroll
        for (int j = 0; j < 8; ++j) acc[j] = (float)self[j];
        unsigned st = off[node], en = off[node + 1];
        unsigned e = st;
        for (; e + 4 <= en; e += 4) {
            float2 p0 = epk[e + 0], p1 = epk[e + 1], p2 = epk[e + 2], p3 = epk[e + 3];
            h8 ga = gp[(size_t)__float_as_int(p0.x) * 5 + f8];
            h8 gb = gp[(size_t)__float_as_int(p1.x) * 5 + f8];
            h8 gc = gp[(size_t)__float_as_int(p2.x) * 5 + f8];
            h8 gd = gp[(size_t)__float_as_int(p3.x) * 5 + f8];
#pragma unroll
            for (int j = 0; j < 8; ++j) acc[j] = fmaf(p0.y, (float)ga[j], acc[j]);
#pragma unroll
            for (int j = 0; j < 8; ++j) acc[j] = fmaf(p1.y, (float)gb[j], acc[j]);
#pragma unroll
            for (int j = 0; j < 8; ++j) acc[j] = fmaf(p2.y, (float)gc[j], acc[j]);
#pragma unroll
            for (int j = 0; j < 8; ++j) acc[j] = fmaf(p3.y, (float)gd[j], acc[j]);
        }
        for (; e < en; ++e) {
            float2 p = epk[e];
            h8 g = gp[(size_t)__float_as_int(p.x) * 5 + f8];
#pragma unroll
            for (int j = 0; j < 8; ++j) acc[j] = fmaf(p.y, (float)g[j], acc[j]);
        }
        float s = dinv[node];
        float4 bv0 = ((const float4*)b)[f8 * 2];
        float4 bv1 = ((const float4*)b)[f8 * 2 + 1];
        const float bb[8] = {bv0.x, bv0.y, bv0.z, bv0.w, bv1.x, bv1.y, bv1.z, bv1.w};
#pragma unroll
        for (int j = 0; j < 8; ++j) {
            acc[j] = fmaf(s, acc[j], bb[j]);
            sm[ln][f8 * 8 + j] = acc[j];
        }
    }
    __syncthreads();
    if (tid < 50) {
        int nd = blockIdx.x * 50 + tid;
        if (nd < n) {
            float m = -INFINITY;
#pragma unroll 8
            for (int j = 0; j < FC; ++j) m = fmaxf(m, sm[tid][j]);
            float sum = 0.f;
#pragma unroll 8
            for (int j = 0; j < FC; ++j) sum += expf(sm[tid][j] - m);
            sm[tid][40] = logf(sum) + m;
        }
    }
    __syncthreads();
    if (active) {
        float lse = sm[ln][40];
        float4 o0 = make_float4(acc[0] - lse, acc[1] - lse, acc[2] - lse, acc[3] - lse);
        float4 o1 = make_float4(acc[4] - lse, acc[5] - lse, acc[6] - lse, acc[7] - lse);
        *(float4*)&out[(size_t)node * FC + f8 * 8] = o0;
        *(float4*)&out[(size_t)node * FC + f8 * 8 + 4] = o1;
    }
}

// ---------------- launch ----------------

extern "C" void kernel_launch(void* const* d_in, const int* in_sizes, int n_in,
                              void* d_out, int out_size, void* d_ws, size_t ws_size,
                              hipStream_t stream) {
    const float* x  = (const float*)d_in[0];
    const int*   ei = (const int*)d_in[1];
    const float* ew = (const float*)d_in[2];
    const float* W1 = (const float*)d_in[3];
    const float* b1 = (const float*)d_in[4];
    const float* W2 = (const float*)d_in[5];
    const float* b2 = (const float*)d_in[6];
    float* out = (float*)d_out;

    const int N = NN;
    const int E = in_sizes[1] / 2;
    const int* row = ei;
    const int* col = ei + E;

    float* ws = (float*)d_ws;
    // workspace layout (4-byte words); total 9,950,976 words = 39.8 MB
    // dinv   [0, 50176)
    // off    [50176, 100480)  N+1
    // bcnt   [100480, 100736) 196 (pad 256)
    // bstart [100736, 100992) 197 (pad 256)
    // gcur   [100992, 101248) 196 (pad 256)
    // overlays of region R = [150976, 4950976):
    //   copies [150976, 1750976) (row-only, 2*64*12500) : k_histcnt -> k_reduce
    //   bkc [150976, 950976), bkrw [950976, 2550976)    : k_bucket -> k_place
    //   h   [150976, 2550976) (fp16 N*96)               : k_agg96 -> k_gemm2
    // epk [4950976, 6550976): k_place -> k_agg40lsm
    // g0h [6550976, 8950976) (fp16 N*96): k_gemm1 -> k_agg96
    // g1h [8950976, 9950976) (fp16 N*40): k_gemm2 -> k_agg40lsm
    float*    dinv   = (float*)(ws + 0);
    unsigned* off    = (unsigned*)(ws + 50176);
    unsigned* bcnt   = (unsigned*)(ws + 100480);
    unsigned* bstart = (unsigned*)(ws + 100736);
    unsigned* gcur   = (unsigned*)(ws + 100992);
    unsigned* copies = (unsigned*)(ws + 150976);
    unsigned* bkc    = (unsigned*)(ws + 150976);
    float2*   bkrw   = (float2*)(ws + 950976);
    _Float16* h      = (_Float16*)(ws + 150976);
    float2*   epk    = (float2*)(ws + 4950976);
    _Float16* g0h    = (_Float16*)(ws + 6550976);
    _Float16* g1h    = (_Float16*)(ws + 8950976);

    const int B = 256;

    hipMemsetAsync(bcnt, 0, 256 * sizeof(unsigned), stream);

    hipLaunchKernelGGL(k_histcnt, dim3(192), dim3(B), 0, stream, ei, E, copies, bcnt);
    hipLaunchKernelGGL(k_reduce, dim3(98), dim3(B), 0, stream,
                       copies, bcnt, dinv, bstart, gcur, off, (unsigned)E);

    hipLaunchKernelGGL(k_bucket, dim3(320), dim3(B), 0, stream, row, col, ew, gcur, bkc, bkrw, E);
    hipLaunchKernelGGL(k_place, dim3(NBK), dim3(B), 0, stream, bkc, bkrw, bstart, off, epk, N);

    hipLaunchKernelGGL(k_gemm1, dim3((N + 63) / 64), dim3(B), 0, stream, x, W1, dinv, g0h, N);

    hipLaunchKernelGGL(k_agg96, dim3((N * 12 + B - 1) / B), dim3(B), 0, stream,
                       g0h, off, epk, dinv, b1, h, N);

    hipLaunchKernelGGL(k_gemm2, dim3((N + 63) / 64), dim3(B), 0, stream, h, W2, dinv, g1h, N);

    hipLaunchKernelGGL(k_agg40lsm, dim3((N + 49) / 50), dim3(B), 0, stream,
                       g1h, off, epk, dinv, b2, out, N);
}

// Round 13
// 139.658 us; speedup vs baseline: 1.1764x; 1.0181x over previous
//
#include <hip/hip_runtime.h>
#include <hip/hip_bf16.h>
#include <hip/hip_fp16.h>
#include <math.h>

#define NN 50000
#define EE 800000
#define FIN 256
#define FH 96
#define FC 40
#define NBK 196   // ceil(50000/256) buckets of 256 nodes

typedef _Float16 h4 __attribute__((ext_vector_type(4)));
typedef _Float16 h8 __attribute__((ext_vector_type(8)));
typedef float f32x4 __attribute__((ext_vector_type(4)));

// pack: low16 = row (N<65536), high16 = fp16 bits of ew
__device__ __forceinline__ unsigned pack_edge(int row, float ew) {
    _Float16 he = (_Float16)ew;
    unsigned short us;
    __builtin_memcpy(&us, &he, 2);
    return (unsigned)row | ((unsigned)us << 16);
}
__device__ __forceinline__ float unpack_w(unsigned pk) {
    unsigned short us = (unsigned short)(pk >> 16);
    _Float16 hv;
    __builtin_memcpy(&hv, &us, 2);
    return (float)hv;
}

// ---------------- fused: row-degree LDS histogram (blocks 0-127) + col bucket-count (blocks 128-191) ----------------

__global__ __launch_bounds__(256) void k_histcnt(const int* __restrict__ ei, int E,
                                                 unsigned* __restrict__ copies,
                                                 unsigned* __restrict__ bcnt) {
    __shared__ unsigned lds[12500];
    int b = blockIdx.x;
    int tid = threadIdx.x;
    int ES = (E + 63) >> 6;
    if (b < 128) {
        int slice = b & 63, half = b >> 6;
        const int* ptr = ei;  // row
        for (int i = tid; i < 12500; i += 256) lds[i] = 0u;
        __syncthreads();
        int lo = slice * ES, hi = min(lo + ES, E);
        int nlo = half * 25000;
        for (int i = lo + tid; i < hi; i += 256) {
            int rel = ptr[i] - nlo;
            if ((unsigned)rel < 25000u)
                atomicAdd(&lds[rel >> 1], 1u << ((rel & 1) << 4));
        }
        __syncthreads();
        unsigned* dst = copies + (size_t)(half * 64 + slice) * 12500;
        for (int i = tid; i < 12500; i += 256) dst[i] = lds[i];
    } else {
        int chunk = b - 128;
        const int* col = ei + E;
        for (int i = tid; i < NBK; i += 256) lds[i] = 0u;
        __syncthreads();
        int lo = chunk * ES, hi = min(lo + ES, E);
        for (int i = lo + tid; i < hi; i += 256) atomicAdd(&lds[col[i] >> 8], 1u);
        __syncthreads();
        for (int i = tid; i < NBK; i += 256)
            if (lds[i]) atomicAdd(&bcnt[i], lds[i]);
    }
}

// ---------------- reduce row-copies -> dinv; block 0 also scans bcnt -> bstart/gcur ----------------

__global__ __launch_bounds__(256) void k_reduce(const unsigned* __restrict__ copies,
                                                const unsigned* __restrict__ bcnt,
                                                float* __restrict__ dinv,
                                                unsigned* __restrict__ bstart,
                                                unsigned* __restrict__ gcur,
                                                unsigned* __restrict__ off, unsigned E) {
    int t = blockIdx.x * blockDim.x + threadIdx.x;  // 0..24999
    if (t < 25000) {
        int half = t / 12500, w = t - half * 12500;
        unsigned sr = 0;
        const unsigned* br = copies + (size_t)half * 64 * 12500 + w;
#pragma unroll 8
        for (int s = 0; s < 64; ++s) sr += br[s * 12500];
        int n0 = half * 25000 + 2 * w;
        dinv[n0]     = rsqrtf((float)((sr & 0xffffu) + 1u));
        dinv[n0 + 1] = rsqrtf((float)((sr >> 16) + 1u));
    }
    if (blockIdx.x == 0) {
        __shared__ unsigned sb[256];
        int tt = threadIdx.x;
        unsigned v = (tt < NBK) ? bcnt[tt] : 0u;
        sb[tt] = v;
        __syncthreads();
        for (int o = 1; o < 256; o <<= 1) {
            unsigned tv = (tt >= o) ? sb[tt - o] : 0u;
            __syncthreads();
            sb[tt] += tv;
            __syncthreads();
        }
        if (tt < NBK) {
            unsigned ex = sb[tt] - v;     // exclusive
            bstart[tt] = ex;
            gcur[tt] = ex;
            bstart[tt + 1] = sb[tt];      // inclusive -> next bucket start
        }
        if (tt == 0) off[NN] = E;
    }
}

// ---------------- P1: coarse bucket by col>>8 (count, reserve, place; packed payload) ----------------

__global__ __launch_bounds__(256) void k_bucket(const int* __restrict__ row,
                                                const int* __restrict__ col,
                                                const float* __restrict__ ew,
                                                unsigned* __restrict__ gcur,
                                                unsigned* __restrict__ bkc,
                                                unsigned* __restrict__ bkpk, int E) {
    __shared__ unsigned cnt[NBK];
    __shared__ unsigned cur[NBK];
    int tid = threadIdx.x;
    int CH = (E + gridDim.x - 1) / gridDim.x;
    int lo = blockIdx.x * CH, hi = min(lo + CH, E);
    for (int i = tid; i < NBK; i += 256) cnt[i] = 0u;
    __syncthreads();
    for (int i = lo + tid; i < hi; i += 256) atomicAdd(&cnt[col[i] >> 8], 1u);
    __syncthreads();
    for (int i = tid; i < NBK; i += 256) cur[i] = atomicAdd(&gcur[i], cnt[i]);
    __syncthreads();
    for (int i = lo + tid; i < hi; i += 256) {
        int c = col[i];
        unsigned pos = atomicAdd(&cur[c >> 8], 1u);
        bkc[pos] = (unsigned)c;
        bkpk[pos] = pack_edge(row[i], ew[i]);
    }
}

// ---------------- P2: per-bucket count + scan -> off[], then exact place (u32 payload) ----------------

__global__ __launch_bounds__(256) void k_place(const unsigned* __restrict__ bkc,
                                               const unsigned* __restrict__ bkpk,
                                               const unsigned* __restrict__ bstart,
                                               unsigned* __restrict__ off,
                                               unsigned* __restrict__ epk, int n) {
    __shared__ unsigned cnt[256];
    __shared__ unsigned cur[256];
    int b = blockIdx.x;
    int tid = threadIdx.x;
    int node0 = b * 256;
    unsigned st = bstart[b], en = bstart[b + 1];
    cnt[tid] = 0u;
    __syncthreads();
    for (unsigned i = st + tid; i < en; i += 256) atomicAdd(&cnt[bkc[i] & 255], 1u);
    __syncthreads();
    unsigned v = cnt[tid];
    cur[tid] = v;
    __syncthreads();
    for (int o = 1; o < 256; o <<= 1) {
        unsigned tv = (tid >= o) ? cur[tid - o] : 0u;
        __syncthreads();
        cur[tid] += tv;
        __syncthreads();
    }
    unsigned base = st + cur[tid] - v;
    int node = node0 + tid;
    if (node < n) off[node] = base;
    cur[tid] = base;
    __syncthreads();
    for (unsigned i = st + tid; i < en; i += 256) {
        unsigned c = bkc[i];
        unsigned pos = atomicAdd(&cur[c & 255], 1u);
        epk[pos] = bkpk[i];
    }
}

// ---------------- GEMM1 (MFMA fp16): g0h = fp16( dinv ⊙ (x @ W1^T) ), interleaved N x 96 ----------------

__global__ __launch_bounds__(256) void k_gemm1(const float* __restrict__ x,
                                               const float* __restrict__ W,
                                               const float* __restrict__ dinv,
                                               _Float16* __restrict__ g0h, int n) {
    __shared__ _Float16 xs[64][72];
    __shared__ _Float16 wsm[96][72];
    int tid = threadIdx.x;
    int row0 = blockIdx.x * 64;
    int l = tid & 63, w = tid >> 6;
    int l15 = l & 15, lg = l >> 4;

    f32x4 acc[6];
#pragma unroll
    for (int c = 0; c < 6; ++c) acc[c] = (f32x4)0.f;

    for (int kc = 0; kc < 4; ++kc) {
        int kbase = kc * 64;
#pragma unroll
        for (int i = 0; i < 4; ++i) {
            int it = tid + 256 * i;
            int r = it >> 4, k4 = it & 15;
            float4 v = make_float4(0.f, 0.f, 0.f, 0.f);
            int gr = row0 + r;
            if (gr < n) v = *(const float4*)&x[gr * FIN + kbase + k4 * 4];
            h4 hv = {(_Float16)v.x, (_Float16)v.y, (_Float16)v.z, (_Float16)v.w};
            *(h4*)&xs[r][k4 * 4] = hv;
        }
#pragma unroll
        for (int i = 0; i < 6; ++i) {
            int it = tid + 256 * i;
            int r = it >> 4, k4 = it & 15;
            float4 v = *(const float4*)&W[r * FIN + kbase + k4 * 4];
            h4 hv = {(_Float16)v.x, (_Float16)v.y, (_Float16)v.z, (_Float16)v.w};
            *(h4*)&wsm[r][k4 * 4] = hv;
        }
        __syncthreads();
#pragma unroll
        for (int ks = 0; ks < 2; ++ks) {
            h8 a = *(const h8*)&xs[16 * w + l15][ks * 32 + lg * 8];
#pragma unroll
            for (int ct = 0; ct < 6; ++ct) {
                h8 b = *(const h8*)&wsm[ct * 16 + l15][ks * 32 + lg * 8];
                acc[ct] = __builtin_amdgcn_mfma_f32_16x16x32_f16(a, b, acc[ct], 0, 0, 0);
            }
        }
        __syncthreads();
    }
#pragma unroll
    for (int r = 0; r < 4; ++r) {
        int grow = row0 + 16 * w + lg * 4 + r;
        if (grow < n) {
            float dv = dinv[grow];
#pragma unroll
            for (int ct = 0; ct < 6; ++ct)
                g0h[(size_t)grow * FH + ct * 16 + l15] = (_Float16)(dv * acc[ct][r]);
        }
    }
}

// ---------------- aggregation 96: 12 threads/node, h8 gathers, u32 payload, unroll-4 ----------------

__global__ __launch_bounds__(256) void k_agg96(const _Float16* __restrict__ g0h,
                                               const unsigned* __restrict__ off,
                                               const unsigned* __restrict__ epk,
                                               const float* __restrict__ dinv,
                                               const float* __restrict__ b,
                                               _Float16* __restrict__ outh, int n) {
    int tid = blockIdx.x * 256 + threadIdx.x;
    int node = tid / 12;
    int f8 = tid - node * 12;
    if (node >= n) return;
    const h8* gp = (const h8*)g0h;  // row = 12 h8 chunks
    h8 self = gp[(size_t)node * 12 + f8];
    float acc[8];
#pragma unroll
    for (int j = 0; j < 8; ++j) acc[j] = (float)self[j];
    unsigned st = off[node], en = off[node + 1];
    unsigned e = st;
    for (; e + 4 <= en; e += 4) {
        unsigned k0 = epk[e + 0], k1 = epk[e + 1], k2 = epk[e + 2], k3 = epk[e + 3];
        h8 ga = gp[(size_t)(k0 & 0xffffu) * 12 + f8];
        h8 gb = gp[(size_t)(k1 & 0xffffu) * 12 + f8];
        h8 gc = gp[(size_t)(k2 & 0xffffu) * 12 + f8];
        h8 gd = gp[(size_t)(k3 & 0xffffu) * 12 + f8];
        float w0 = unpack_w(k0), w1 = unpack_w(k1), w2 = unpack_w(k2), w3 = unpack_w(k3);
#pragma unroll
        for (int j = 0; j < 8; ++j) acc[j] = fmaf(w0, (float)ga[j], acc[j]);
#pragma unroll
        for (int j = 0; j < 8; ++j) acc[j] = fmaf(w1, (float)gb[j], acc[j]);
#pragma unroll
        for (int j = 0; j < 8; ++j) acc[j] = fmaf(w2, (float)gc[j], acc[j]);
#pragma unroll
        for (int j = 0; j < 8; ++j) acc[j] = fmaf(w3, (float)gd[j], acc[j]);
    }
    for (; e < en; ++e) {
        unsigned k = epk[e];
        h8 g = gp[(size_t)(k & 0xffffu) * 12 + f8];
        float wv = unpack_w(k);
#pragma unroll
        for (int j = 0; j < 8; ++j) acc[j] = fmaf(wv, (float)g[j], acc[j]);
    }
    float s = dinv[node];
    float4 bv0 = ((const float4*)b)[f8 * 2];
    float4 bv1 = ((const float4*)b)[f8 * 2 + 1];
    const float bb[8] = {bv0.x, bv0.y, bv0.z, bv0.w, bv1.x, bv1.y, bv1.z, bv1.w};
    h8 o;
#pragma unroll
    for (int j = 0; j < 8; ++j) o[j] = (_Float16)fmaxf(fmaf(s, acc[j], bb[j]), 0.f);
    *(h8*)&outh[(size_t)node * FH + f8 * 8] = o;
}

// ---------------- GEMM2 (MFMA fp16): g1h = fp16( dinv ⊙ (h @ W2^T) ) ----------------

__global__ __launch_bounds__(256) void k_gemm2(const _Float16* __restrict__ h,
                                               const float* __restrict__ W2,
                                               const float* __restrict__ dinv,
                                               _Float16* __restrict__ g1h, int n) {
    __shared__ _Float16 hs[64][104];
    __shared__ _Float16 wsm[48][104];
    int tid = threadIdx.x;
    int row0 = blockIdx.x * 64;
    int l = tid & 63, w = tid >> 6;
    int l15 = l & 15, lg = l >> 4;

    f32x4 acc[3];
#pragma unroll
    for (int c = 0; c < 3; ++c) acc[c] = (f32x4)0.f;

#pragma unroll
    for (int i = 0; i < 6; ++i) {
        int it = tid + 256 * i;
        int r = it / 24, k4 = it - r * 24;
        int gr = row0 + r;
        h4 hv = {(_Float16)0.f, (_Float16)0.f, (_Float16)0.f, (_Float16)0.f};
        if (gr < n) hv = *(const h4*)&h[(size_t)gr * FH + k4 * 4];
        *(h4*)&hs[r][k4 * 4] = hv;
    }
#pragma unroll
    for (int i = 0; i < 5; ++i) {
        int it = tid + 256 * i;
        if (it < 1152) {
            int r = it / 24, k4 = it - r * 24;
            h4 hv = {(_Float16)0.f, (_Float16)0.f, (_Float16)0.f, (_Float16)0.f};
            if (r < FC) {
                float4 v = *(const float4*)&W2[r * FH + k4 * 4];
                hv[0] = (_Float16)v.x; hv[1] = (_Float16)v.y;
                hv[2] = (_Float16)v.z; hv[3] = (_Float16)v.w;
            }
            *(h4*)&wsm[r][k4 * 4] = hv;
        }
    }
    __syncthreads();
#pragma unroll
    for (int ks = 0; ks < 3; ++ks) {
        h8 a = *(const h8*)&hs[16 * w + l15][ks * 32 + lg * 8];
#pragma unroll
        for (int ct = 0; ct < 3; ++ct) {
            h8 b = *(const h8*)&wsm[ct * 16 + l15][ks * 32 + lg * 8];
            acc[ct] = __builtin_amdgcn_mfma_f32_16x16x32_f16(a, b, acc[ct], 0, 0, 0);
        }
    }
#pragma unroll
    for (int r = 0; r < 4; ++r) {
        int grow = row0 + 16 * w + lg * 4 + r;
        if (grow < n) {
            float dv = dinv[grow];
#pragma unroll
            for (int ct = 0; ct < 3; ++ct) {
                int colc = ct * 16 + l15;
                if (colc < FC)
                    g1h[(size_t)grow * FC + colc] = (_Float16)(dv * acc[ct][r]);
            }
        }
    }
}

// ---------------- aggregation 40 + log_softmax fused: 5 threads/node h8, 50 nodes/block ----------------

__global__ __launch_bounds__(256) void k_agg40lsm(const _Float16* __restrict__ g1h,
                                                  const unsigned* __restrict__ off,
                                                  const unsigned* __restrict__ epk,
                                                  const float* __restrict__ dinv,
                                                  const float* __restrict__ b,
                                                  float* __restrict__ out, int n) {
    __shared__ float sm[50][41];
    int tid = threadIdx.x;
    int ln = tid / 5;
    int f8 = tid - ln * 5;
    int node = blockIdx.x * 50 + ln;
    bool active = (tid < 250) && (node < n);
    float acc[8];
#pragma unroll
    for (int j = 0; j < 8; ++j) acc[j] = 0.f;
    if (active) {
        const h8* gp = (const h8*)g1h;  // row = 5 h8 chunks
        h8 self = gp[(size_t)node * 5 + f8];
#pragma unroll
        for (int j = 0; j < 8; ++j) acc[j] = (float)self[j];
        unsigned st = off[node], en = off[node + 1];
        unsigned e = st;
        for (; e + 4 <= en; e += 4) {
            unsigned k0 = epk[e + 0], k1 = epk[e + 1], k2 = epk[e + 2], k3 = epk[e + 3];
            h8 ga = gp[(size_t)(k0 & 0xffffu) * 5 + f8];
            h8 gb = gp[(size_t)(k1 & 0xffffu) * 5 + f8];
            h8 gc = gp[(size_t)(k2 & 0xffffu) * 5 + f8];
            h8 gd = gp[(size_t)(k3 & 0xffffu) * 5 + f8];
            float w0 = unpack_w(k0), w1 = unpack_w(k1), w2 = unpack_w(k2), w3 = unpack_w(k3);
#pragma unroll
            for (int j = 0; j < 8; ++j) acc[j] = fmaf(w0, (float)ga[j], acc[j]);
#pragma unroll
            for (int j = 0; j < 8; ++j) acc[j] = fmaf(w1, (float)gb[j], acc[j]);
#pragma unroll
            for (int j = 0; j < 8; ++j) acc[j] = fmaf(w2, (float)gc[j], acc[j]);
#pragma unroll
            for (int j = 0; j < 8; ++j) acc[j] = fmaf(w3, (float)gd[j], acc[j]);
        }
        for (; e < en; ++e) {
            unsigned k = epk[e];
            h8 g = gp[(size_t)(k & 0xffffu) * 5 + f8];
            float wv = unpack_w(k);
#pragma unroll
            for (int j = 0; j < 8; ++j) acc[j] = fmaf(wv, (float)g[j], acc[j]);
        }
        float s = dinv[node];
        float4 bv0 = ((const float4*)b)[f8 * 2];
        float4 bv1 = ((const float4*)b)[f8 * 2 + 1];
        const float bb[8] = {bv0.x, bv0.y, bv0.z, bv0.w, bv1.x, bv1.y, bv1.z, bv1.w};
#pragma unroll
        for (int j = 0; j < 8; ++j) {
            acc[j] = fmaf(s, acc[j], bb[j]);
            sm[ln][f8 * 8 + j] = acc[j];
        }
    }
    __syncthreads();
    if (tid < 50) {
        int nd = blockIdx.x * 50 + tid;
        if (nd < n) {
            float m = -INFINITY;
#pragma unroll 8
            for (int j = 0; j < FC; ++j) m = fmaxf(m, sm[tid][j]);
            float sum = 0.f;
#pragma unroll 8
            for (int j = 0; j < FC; ++j) sum += expf(sm[tid][j] - m);
            sm[tid][40] = logf(sum) + m;
        }
    }
    __syncthreads();
    if (active) {
        float lse = sm[ln][40];
        float4 o0 = make_float4(acc[0] - lse, acc[1] - lse, acc[2] - lse, acc[3] - lse);
        float4 o1 = make_float4(acc[4] - lse, acc[5] - lse, acc[6] - lse, acc[7] - lse);
        *(float4*)&out[(size_t)node * FC + f8 * 8] = o0;
        *(float4*)&out[(size_t)node * FC + f8 * 8 + 4] = o1;
    }
}

// ---------------- launch ----------------

extern "C" void kernel_launch(void* const* d_in, const int* in_sizes, int n_in,
                              void* d_out, int out_size, void* d_ws, size_t ws_size,
                              hipStream_t stream) {
    const float* x  = (const float*)d_in[0];
    const int*   ei = (const int*)d_in[1];
    const float* ew = (const float*)d_in[2];
    const float* W1 = (const float*)d_in[3];
    const float* b1 = (const float*)d_in[4];
    const float* W2 = (const float*)d_in[5];
    const float* b2 = (const float*)d_in[6];
    float* out = (float*)d_out;

    const int N = NN;
    const int E = in_sizes[1] / 2;
    const int* row = ei;
    const int* col = ei + E;

    float* ws = (float*)d_ws;
    // workspace layout (4-byte words)
    // dinv   [0, 50176)
    // off    [50176, 100480)  N+1
    // bcnt   [100480, 100736)
    // bstart [100736, 100992)
    // gcur   [100992, 101248)
    // overlays of region R = [150976, 4950976):
    //   copies [150976, 1750976)                        : k_histcnt -> k_reduce
    //   bkc [150976, 950976), bkpk [950976, 1750976)    : k_bucket -> k_place
    //   h   [150976, 2550976) (fp16 N*96)               : k_agg96 -> k_gemm2
    // epk [4950976, 5750976) u32: k_place -> k_agg40lsm
    // g0h [6550976, 8950976) (fp16 N*96): k_gemm1 -> k_agg96
    // g1h [8950976, 9950976) (fp16 N*40): k_gemm2 -> k_agg40lsm
    float*    dinv   = (float*)(ws + 0);
    unsigned* off    = (unsigned*)(ws + 50176);
    unsigned* bcnt   = (unsigned*)(ws + 100480);
    unsigned* bstart = (unsigned*)(ws + 100736);
    unsigned* gcur   = (unsigned*)(ws + 100992);
    unsigned* copies = (unsigned*)(ws + 150976);
    unsigned* bkc    = (unsigned*)(ws + 150976);
    unsigned* bkpk   = (unsigned*)(ws + 950976);
    _Float16* h      = (_Float16*)(ws + 150976);
    unsigned* epk    = (unsigned*)(ws + 4950976);
    _Float16* g0h    = (_Float16*)(ws + 6550976);
    _Float16* g1h    = (_Float16*)(ws + 8950976);

    const int B = 256;

    hipMemsetAsync(bcnt, 0, 256 * sizeof(unsigned), stream);

    hipLaunchKernelGGL(k_histcnt, dim3(192), dim3(B), 0, stream, ei, E, copies, bcnt);
    hipLaunchKernelGGL(k_reduce, dim3(98), dim3(B), 0, stream,
                       copies, bcnt, dinv, bstart, gcur, off, (unsigned)E);

    hipLaunchKernelGGL(k_bucket, dim3(320), dim3(B), 0, stream, row, col, ew, gcur, bkc, bkpk, E);
    hipLaunchKernelGGL(k_place, dim3(NBK), dim3(B), 0, stream, bkc, bkpk, bstart, off, epk, N);

    hipLaunchKernelGGL(k_gemm1, dim3((N + 63) / 64), dim3(B), 0, stream, x, W1, dinv, g0h, N);

    hipLaunchKernelGGL(k_agg96, dim3((N * 12 + B - 1) / B), dim3(B), 0, stream,
                       g0h, off, epk, dinv, b1, h, N);

    hipLaunchKernelGGL(k_gemm2, dim3((N + 63) / 64), dim3(B), 0, stream, h, W2, dinv, g1h, N);

    hipLaunchKernelGGL(k_agg40lsm, dim3((N + 49) / 50), dim3(B), 0, stream,
                       g1h, off, epk, dinv, b2, out, N);
}

// Round 14
// 130.554 us; speedup vs baseline: 1.2584x; 1.0697x over previous
//
#include <hip/hip_runtime.h>
#include <hip/hip_bf16.h>
#include <hip/hip_fp16.h>
#include <math.h>

#define NN 50000
#define EE 800000
#define FIN 256
#define FH 96
#define FC 40
#define NBK 196   // ceil(50000/256) buckets of 256 nodes

typedef _Float16 h4 __attribute__((ext_vector_type(4)));
typedef _Float16 h8 __attribute__((ext_vector_type(8)));
typedef float f32x4 __attribute__((ext_vector_type(4)));

// pack: low16 = row (N<65536), high16 = fp16 bits of w (= dinv[row]*ew)
__device__ __forceinline__ unsigned pack_edge(int row, float w) {
    _Float16 he = (_Float16)w;
    unsigned short us;
    __builtin_memcpy(&us, &he, 2);
    return (unsigned)row | ((unsigned)us << 16);
}
__device__ __forceinline__ float unpack_w(unsigned pk) {
    unsigned short us = (unsigned short)(pk >> 16);
    _Float16 hv;
    __builtin_memcpy(&hv, &us, 2);
    return (float)hv;
}

// ---------------- fused launch 1 ----------------
// blocks [0,782): GEMM1 (MFMA fp16, raw x@W1^T, no dinv)
// blocks [782,910): row-degree LDS histogram (16-bit packed)
// blocks [910,974): col bucket-count -> private bcnt2d rows (no atomics, no memset)

#define G1B 782

__global__ __launch_bounds__(256) void k_fused1(const float* __restrict__ x,
                                                const float* __restrict__ W,
                                                _Float16* __restrict__ g0h,
                                                const int* __restrict__ ei, int E,
                                                unsigned* __restrict__ copies,
                                                unsigned* __restrict__ bcnt2d, int n) {
    __shared__ unsigned lds[12500];
    int bid = blockIdx.x;
    int tid = threadIdx.x;

    if (bid < G1B) {
        // ---- GEMM1 ----
        _Float16* xsp = (_Float16*)lds;          // [64][72]
        _Float16* wsp = xsp + 64 * 72;           // [96][72]
        int row0 = bid * 64;
        int l = tid & 63, w = tid >> 6;
        int l15 = l & 15, lg = l >> 4;

        f32x4 acc[6];
#pragma unroll
        for (int c = 0; c < 6; ++c) acc[c] = (f32x4)0.f;

        for (int kc = 0; kc < 4; ++kc) {
            int kbase = kc * 64;
#pragma unroll
            for (int i = 0; i < 4; ++i) {
                int it = tid + 256 * i;
                int r = it >> 4, k4 = it & 15;
                float4 v = make_float4(0.f, 0.f, 0.f, 0.f);
                int gr = row0 + r;
                if (gr < n) v = *(const float4*)&x[gr * FIN + kbase + k4 * 4];
                h4 hv = {(_Float16)v.x, (_Float16)v.y, (_Float16)v.z, (_Float16)v.w};
                *(h4*)&xsp[r * 72 + k4 * 4] = hv;
            }
#pragma unroll
            for (int i = 0; i < 6; ++i) {
                int it = tid + 256 * i;
                int r = it >> 4, k4 = it & 15;
                float4 v = *(const float4*)&W[r * FIN + kbase + k4 * 4];
                h4 hv = {(_Float16)v.x, (_Float16)v.y, (_Float16)v.z, (_Float16)v.w};
                *(h4*)&wsp[r * 72 + k4 * 4] = hv;
            }
            __syncthreads();
#pragma unroll
            for (int ks = 0; ks < 2; ++ks) {
                h8 a = *(const h8*)&xsp[(16 * w + l15) * 72 + ks * 32 + lg * 8];
#pragma unroll
                for (int ct = 0; ct < 6; ++ct) {
                    h8 b = *(const h8*)&wsp[(ct * 16 + l15) * 72 + ks * 32 + lg * 8];
                    acc[ct] = __builtin_amdgcn_mfma_f32_16x16x32_f16(a, b, acc[ct], 0, 0, 0);
                }
            }
            __syncthreads();
        }
#pragma unroll
        for (int r = 0; r < 4; ++r) {
            int grow = row0 + 16 * w + lg * 4 + r;
            if (grow < n) {
#pragma unroll
                for (int ct = 0; ct < 6; ++ct)
                    g0h[(size_t)grow * FH + ct * 16 + l15] = (_Float16)acc[ct][r];
            }
        }
    } else if (bid < 910) {
        // ---- row-degree histogram ----
        int b2 = bid - G1B;
        int slice = b2 & 63, half = b2 >> 6;
        int ES = (E + 63) >> 6;
        const int* ptr = ei;  // row
        for (int i = tid; i < 12500; i += 256) lds[i] = 0u;
        __syncthreads();
        int lo = slice * ES, hi = min(lo + ES, E);
        int nlo = half * 25000;
        for (int i = lo + tid; i < hi; i += 256) {
            int rel = ptr[i] - nlo;
            if ((unsigned)rel < 25000u)
                atomicAdd(&lds[rel >> 1], 1u << ((rel & 1) << 4));
        }
        __syncthreads();
        unsigned* dst = copies + (size_t)(half * 64 + slice) * 12500;
        for (int i = tid; i < 12500; i += 256) dst[i] = lds[i];
    } else {
        // ---- col bucket-count (private row per chunk) ----
        int chunk = bid - 910;
        int ES = (E + 63) >> 6;
        const int* col = ei + E;
        for (int i = tid; i < NBK; i += 256) lds[i] = 0u;
        __syncthreads();
        int lo = chunk * ES, hi = min(lo + ES, E);
        for (int i = lo + tid; i < hi; i += 256) atomicAdd(&lds[col[i] >> 8], 1u);
        __syncthreads();
        for (int i = tid; i < NBK; i += 256) bcnt2d[chunk * 256 + i] = lds[i];
    }
}

// ---------------- reduce row-copies -> dinv; block 0 sums bcnt2d + scans -> bstart/gcur ----------------

__global__ __launch_bounds__(256) void k_reduce(const unsigned* __restrict__ copies,
                                                const unsigned* __restrict__ bcnt2d,
                                                float* __restrict__ dinv,
                                                unsigned* __restrict__ bstart,
                                                unsigned* __restrict__ gcur,
                                                unsigned* __restrict__ off, unsigned E) {
    int t = blockIdx.x * blockDim.x + threadIdx.x;  // 0..24999
    if (t < 25000) {
        int half = t / 12500, w = t - half * 12500;
        unsigned sr = 0;
        const unsigned* br = copies + (size_t)half * 64 * 12500 + w;
#pragma unroll 8
        for (int s = 0; s < 64; ++s) sr += br[s * 12500];
        int n0 = half * 25000 + 2 * w;
        dinv[n0]     = rsqrtf((float)((sr & 0xffffu) + 1u));
        dinv[n0 + 1] = rsqrtf((float)((sr >> 16) + 1u));
    }
    if (blockIdx.x == 0) {
        __shared__ unsigned sb[256];
        int tt = threadIdx.x;
        unsigned v = 0;
        if (tt < NBK) {
#pragma unroll 8
            for (int c = 0; c < 64; ++c) v += bcnt2d[c * 256 + tt];
        }
        sb[tt] = v;
        __syncthreads();
        for (int o = 1; o < 256; o <<= 1) {
            unsigned tv = (tt >= o) ? sb[tt - o] : 0u;
            __syncthreads();
            sb[tt] += tv;
            __syncthreads();
        }
        if (tt < NBK) {
            unsigned ex = sb[tt] - v;     // exclusive
            bstart[tt] = ex;
            gcur[tt] = ex;
            bstart[tt + 1] = sb[tt];
        }
        if (tt == 0) off[NN] = E;
    }
}

// ---------------- P1: coarse bucket by col>>8; payload packs dinv[row]*ew ----------------

__global__ __launch_bounds__(256) void k_bucket(const int* __restrict__ row,
                                                const int* __restrict__ col,
                                                const float* __restrict__ ew,
                                                const float* __restrict__ dinv,
                                                unsigned* __restrict__ gcur,
                                                unsigned* __restrict__ bkc,
                                                unsigned* __restrict__ bkpk, int E) {
    __shared__ unsigned cnt[NBK];
    __shared__ unsigned cur[NBK];
    int tid = threadIdx.x;
    int CH = (E + gridDim.x - 1) / gridDim.x;
    int lo = blockIdx.x * CH, hi = min(lo + CH, E);
    for (int i = tid; i < NBK; i += 256) cnt[i] = 0u;
    __syncthreads();
    for (int i = lo + tid; i < hi; i += 256) atomicAdd(&cnt[col[i] >> 8], 1u);
    __syncthreads();
    for (int i = tid; i < NBK; i += 256) cur[i] = atomicAdd(&gcur[i], cnt[i]);
    __syncthreads();
    for (int i = lo + tid; i < hi; i += 256) {
        int c = col[i];
        int r = row[i];
        unsigned pos = atomicAdd(&cur[c >> 8], 1u);
        bkc[pos] = (unsigned)c;
        bkpk[pos] = pack_edge(r, dinv[r] * ew[i]);
    }
}

// ---------------- P2: per-bucket count + scan -> off[], then exact place ----------------

__global__ __launch_bounds__(256) void k_place(const unsigned* __restrict__ bkc,
                                               const unsigned* __restrict__ bkpk,
                                               const unsigned* __restrict__ bstart,
                                               unsigned* __restrict__ off,
                                               unsigned* __restrict__ epk, int n) {
    __shared__ unsigned cnt[256];
    __shared__ unsigned cur[256];
    int b = blockIdx.x;
    int tid = threadIdx.x;
    int node0 = b * 256;
    unsigned st = bstart[b], en = bstart[b + 1];
    cnt[tid] = 0u;
    __syncthreads();
    for (unsigned i = st + tid; i < en; i += 256) atomicAdd(&cnt[bkc[i] & 255], 1u);
    __syncthreads();
    unsigned v = cnt[tid];
    cur[tid] = v;
    __syncthreads();
    for (int o = 1; o < 256; o <<= 1) {
        unsigned tv = (tid >= o) ? cur[tid - o] : 0u;
        __syncthreads();
        cur[tid] += tv;
        __syncthreads();
    }
    unsigned base = st + cur[tid] - v;
    int node = node0 + tid;
    if (node < n) off[node] = base;
    cur[tid] = base;
    __syncthreads();
    for (unsigned i = st + tid; i < en; i += 256) {
        unsigned c = bkc[i];
        unsigned pos = atomicAdd(&cur[c & 255], 1u);
        epk[pos] = bkpk[i];
    }
}

// ---------------- aggregation 96: 12 threads/node, h8 gathers, unroll-8/4, s^2 self ----------------

__global__ __launch_bounds__(256) void k_agg96(const _Float16* __restrict__ g0h,
                                               const unsigned* __restrict__ off,
                                               const unsigned* __restrict__ epk,
                                               const float* __restrict__ dinv,
                                               const float* __restrict__ b,
                                               _Float16* __restrict__ outh, int n) {
    int tid = blockIdx.x * 256 + threadIdx.x;
    int node = tid / 12;
    int f8 = tid - node * 12;
    if (node >= n) return;
    float s = dinv[node];
    const h8* gp = (const h8*)g0h;  // row = 12 h8 chunks
    h8 self = gp[(size_t)node * 12 + f8];
    float acc[8];
#pragma unroll
    for (int j = 0; j < 8; ++j) acc[j] = s * (float)self[j];
    unsigned st = off[node], en = off[node + 1];
    unsigned e = st;
    for (; e + 8 <= en; e += 8) {
        unsigned k0 = epk[e + 0], k1 = epk[e + 1], k2 = epk[e + 2], k3 = epk[e + 3];
        unsigned k4 = epk[e + 4], k5 = epk[e + 5], k6 = epk[e + 6], k7 = epk[e + 7];
        h8 ga = gp[(size_t)(k0 & 0xffffu) * 12 + f8];
        h8 gb = gp[(size_t)(k1 & 0xffffu) * 12 + f8];
        h8 gc = gp[(size_t)(k2 & 0xffffu) * 12 + f8];
        h8 gd = gp[(size_t)(k3 & 0xffffu) * 12 + f8];
        h8 ge = gp[(size_t)(k4 & 0xffffu) * 12 + f8];
        h8 gf = gp[(size_t)(k5 & 0xffffu) * 12 + f8];
        h8 gg = gp[(size_t)(k6 & 0xffffu) * 12 + f8];
        h8 gh = gp[(size_t)(k7 & 0xffffu) * 12 + f8];
        float w0 = unpack_w(k0), w1 = unpack_w(k1), w2 = unpack_w(k2), w3 = unpack_w(k3);
        float w4 = unpack_w(k4), w5 = unpack_w(k5), w6 = unpack_w(k6), w7 = unpack_w(k7);
#pragma unroll
        for (int j = 0; j < 8; ++j) acc[j] = fmaf(w0, (float)ga[j], acc[j]);
#pragma unroll
        for (int j = 0; j < 8; ++j) acc[j] = fmaf(w1, (float)gb[j], acc[j]);
#pragma unroll
        for (int j = 0; j < 8; ++j) acc[j] = fmaf(w2, (float)gc[j], acc[j]);
#pragma unroll
        for (int j = 0; j < 8; ++j) acc[j] = fmaf(w3, (float)gd[j], acc[j]);
#pragma unroll
        for (int j = 0; j < 8; ++j) acc[j] = fmaf(w4, (float)ge[j], acc[j]);
#pragma unroll
        for (int j = 0; j < 8; ++j) acc[j] = fmaf(w5, (float)gf[j], acc[j]);
#pragma unroll
        for (int j = 0; j < 8; ++j) acc[j] = fmaf(w6, (float)gg[j], acc[j]);
#pragma unroll
        for (int j = 0; j < 8; ++j) acc[j] = fmaf(w7, (float)gh[j], acc[j]);
    }
    for (; e + 4 <= en; e += 4) {
        unsigned k0 = epk[e + 0], k1 = epk[e + 1], k2 = epk[e + 2], k3 = epk[e + 3];
        h8 ga = gp[(size_t)(k0 & 0xffffu) * 12 + f8];
        h8 gb = gp[(size_t)(k1 & 0xffffu) * 12 + f8];
        h8 gc = gp[(size_t)(k2 & 0xffffu) * 12 + f8];
        h8 gd = gp[(size_t)(k3 & 0xffffu) * 12 + f8];
        float w0 = unpack_w(k0), w1 = unpack_w(k1), w2 = unpack_w(k2), w3 = unpack_w(k3);
#pragma unroll
        for (int j = 0; j < 8; ++j) acc[j] = fmaf(w0, (float)ga[j], acc[j]);
#pragma unroll
        for (int j = 0; j < 8; ++j) acc[j] = fmaf(w1, (float)gb[j], acc[j]);
#pragma unroll
        for (int j = 0; j < 8; ++j) acc[j] = fmaf(w2, (float)gc[j], acc[j]);
#pragma unroll
        for (int j = 0; j < 8; ++j) acc[j] = fmaf(w3, (float)gd[j], acc[j]);
    }
    for (; e < en; ++e) {
        unsigned k = epk[e];
        h8 g = gp[(size_t)(k & 0xffffu) * 12 + f8];
        float wv = unpack_w(k);
#pragma unroll
        for (int j = 0; j < 8; ++j) acc[j] = fmaf(wv, (float)g[j], acc[j]);
    }
    float4 bv0 = ((const float4*)b)[f8 * 2];
    float4 bv1 = ((const float4*)b)[f8 * 2 + 1];
    const float bb[8] = {bv0.x, bv0.y, bv0.z, bv0.w, bv1.x, bv1.y, bv1.z, bv1.w};
    h8 o;
#pragma unroll
    for (int j = 0; j < 8; ++j) o[j] = (_Float16)fmaxf(fmaf(s, acc[j], bb[j]), 0.f);
    *(h8*)&outh[(size_t)node * FH + f8 * 8] = o;
}

// ---------------- GEMM2 (MFMA fp16): g1h = fp16( h @ W2^T ) raw, no dinv ----------------

__global__ __launch_bounds__(256) void k_gemm2(const _Float16* __restrict__ h,
                                               const float* __restrict__ W2,
                                               _Float16* __restrict__ g1h, int n) {
    __shared__ _Float16 hs[64][104];
    __shared__ _Float16 wsm[48][104];
    int tid = threadIdx.x;
    int row0 = blockIdx.x * 64;
    int l = tid & 63, w = tid >> 6;
    int l15 = l & 15, lg = l >> 4;

    f32x4 acc[3];
#pragma unroll
    for (int c = 0; c < 3; ++c) acc[c] = (f32x4)0.f;

#pragma unroll
    for (int i = 0; i < 6; ++i) {
        int it = tid + 256 * i;
        int r = it / 24, k4 = it - r * 24;
        int gr = row0 + r;
        h4 hv = {(_Float16)0.f, (_Float16)0.f, (_Float16)0.f, (_Float16)0.f};
        if (gr < n) hv = *(const h4*)&h[(size_t)gr * FH + k4 * 4];
        *(h4*)&hs[r][k4 * 4] = hv;
    }
#pragma unroll
    for (int i = 0; i < 5; ++i) {
        int it = tid + 256 * i;
        if (it < 1152) {
            int r = it / 24, k4 = it - r * 24;
            h4 hv = {(_Float16)0.f, (_Float16)0.f, (_Float16)0.f, (_Float16)0.f};
            if (r < FC) {
                float4 v = *(const float4*)&W2[r * FH + k4 * 4];
                hv[0] = (_Float16)v.x; hv[1] = (_Float16)v.y;
                hv[2] = (_Float16)v.z; hv[3] = (_Float16)v.w;
            }
            *(h4*)&wsm[r][k4 * 4] = hv;
        }
    }
    __syncthreads();
#pragma unroll
    for (int ks = 0; ks < 3; ++ks) {
        h8 a = *(const h8*)&hs[16 * w + l15][ks * 32 + lg * 8];
#pragma unroll
        for (int ct = 0; ct < 3; ++ct) {
            h8 b = *(const h8*)&wsm[ct * 16 + l15][ks * 32 + lg * 8];
            acc[ct] = __builtin_amdgcn_mfma_f32_16x16x32_f16(a, b, acc[ct], 0, 0, 0);
        }
    }
#pragma unroll
    for (int r = 0; r < 4; ++r) {
        int grow = row0 + 16 * w + lg * 4 + r;
        if (grow < n) {
#pragma unroll
            for (int ct = 0; ct < 3; ++ct) {
                int colc = ct * 16 + l15;
                if (colc < FC)
                    g1h[(size_t)grow * FC + colc] = (_Float16)acc[ct][r];
            }
        }
    }
}

// ---------------- aggregation 40 + log_softmax fused: 5 threads/node h8, 50 nodes/block ----------------

__global__ __launch_bounds__(256) void k_agg40lsm(const _Float16* __restrict__ g1h,
                                                  const unsigned* __restrict__ off,
                                                  const unsigned* __restrict__ epk,
                                                  const float* __restrict__ dinv,
                                                  const float* __restrict__ b,
                                                  float* __restrict__ out, int n) {
    __shared__ float sm[50][41];
    int tid = threadIdx.x;
    int ln = tid / 5;
    int f8 = tid - ln * 5;
    int node = blockIdx.x * 50 + ln;
    bool active = (tid < 250) && (node < n);
    float acc[8];
#pragma unroll
    for (int j = 0; j < 8; ++j) acc[j] = 0.f;
    if (active) {
        float s = dinv[node];
        const h8* gp = (const h8*)g1h;  // row = 5 h8 chunks
        h8 self = gp[(size_t)node * 5 + f8];
#pragma unroll
        for (int j = 0; j < 8; ++j) acc[j] = s * (float)self[j];
        unsigned st = off[node], en = off[node + 1];
        unsigned e = st;
        for (; e + 4 <= en; e += 4) {
            unsigned k0 = epk[e + 0], k1 = epk[e + 1], k2 = epk[e + 2], k3 = epk[e + 3];
            h8 ga = gp[(size_t)(k0 & 0xffffu) * 5 + f8];
            h8 gb = gp[(size_t)(k1 & 0xffffu) * 5 + f8];
            h8 gc = gp[(size_t)(k2 & 0xffffu) * 5 + f8];
            h8 gd = gp[(size_t)(k3 & 0xffffu) * 5 + f8];
            float w0 = unpack_w(k0), w1 = unpack_w(k1), w2 = unpack_w(k2), w3 = unpack_w(k3);
#pragma unroll
            for (int j = 0; j < 8; ++j) acc[j] = fmaf(w0, (float)ga[j], acc[j]);
#pragma unroll
            for (int j = 0; j < 8; ++j) acc[j] = fmaf(w1, (float)gb[j], acc[j]);
#pragma unroll
            for (int j = 0; j < 8; ++j) acc[j] = fmaf(w2, (float)gc[j], acc[j]);
#pragma unroll
            for (int j = 0; j < 8; ++j) acc[j] = fmaf(w3, (float)gd[j], acc[j]);
        }
        for (; e < en; ++e) {
            unsigned k = epk[e];
            h8 g = gp[(size_t)(k & 0xffffu) * 5 + f8];
            float wv = unpack_w(k);
#pragma unroll
            for (int j = 0; j < 8; ++j) acc[j] = fmaf(wv, (float)g[j], acc[j]);
        }
        float4 bv0 = ((const float4*)b)[f8 * 2];
        float4 bv1 = ((const float4*)b)[f8 * 2 + 1];
        const float bb[8] = {bv0.x, bv0.y, bv0.z, bv0.w, bv1.x, bv1.y, bv1.z, bv1.w};
#pragma unroll
        for (int j = 0; j < 8; ++j) {
            acc[j] = fmaf(s, acc[j], bb[j]);
            sm[ln][f8 * 8 + j] = acc[j];
        }
    }
    __syncthreads();
    if (tid < 50) {
        int nd = blockIdx.x * 50 + tid;
        if (nd < n) {
            float m = -INFINITY;
#pragma unroll 8
            for (int j = 0; j < FC; ++j) m = fmaxf(m, sm[tid][j]);
            float sum = 0.f;
#pragma unroll 8
            for (int j = 0; j < FC; ++j) sum += expf(sm[tid][j] - m);
            sm[tid][40] = logf(sum) + m;
        }
    }
    __syncthreads();
    if (active) {
        float lse = sm[ln][40];
        float4 o0 = make_float4(acc[0] - lse, acc[1] - lse, acc[2] - lse, acc[3] - lse);
        float4 o1 = make_float4(acc[4] - lse, acc[5] - lse, acc[6] - lse, acc[7] - lse);
        *(float4*)&out[(size_t)node * FC + f8 * 8] = o0;
        *(float4*)&out[(size_t)node * FC + f8 * 8 + 4] = o1;
    }
}

// ---------------- launch ----------------

extern "C" void kernel_launch(void* const* d_in, const int* in_sizes, int n_in,
                              void* d_out, int out_size, void* d_ws, size_t ws_size,
                              hipStream_t stream) {
    const float* x  = (const float*)d_in[0];
    const int*   ei = (const int*)d_in[1];
    const float* ew = (const float*)d_in[2];
    const float* W1 = (const float*)d_in[3];
    const float* b1 = (const float*)d_in[4];
    const float* W2 = (const float*)d_in[5];
    const float* b2 = (const float*)d_in[6];
    float* out = (float*)d_out;

    const int N = NN;
    const int E = in_sizes[1] / 2;
    const int* row = ei;
    const int* col = ei + E;

    float* ws = (float*)d_ws;
    // workspace layout (4-byte words)
    // dinv   [0, 50176)
    // off    [50176, 100480)  N+1
    // bcnt2d [100480, 116864) 64x256
    // bstart [116864, 117120)
    // gcur   [117120, 117376)
    // overlays of region R = [150976, 4950976):
    //   copies [150976, 1750976)                        : k_fused1 -> k_reduce
    //   bkc [150976, 950976), bkpk [950976, 1750976)    : k_bucket -> k_place
    //   h   [150976, 2550976) (fp16 N*96)               : k_agg96 -> k_gemm2
    // epk [4950976, 5750976) u32: k_place -> k_agg40lsm
    // g0h [6550976, 8950976) (fp16 N*96 raw): k_fused1 -> k_agg96
    // g1h [8950976, 9950976) (fp16 N*40 raw): k_gemm2 -> k_agg40lsm
    float*    dinv   = (float*)(ws + 0);
    unsigned* off    = (unsigned*)(ws + 50176);
    unsigned* bcnt2d = (unsigned*)(ws + 100480);
    unsigned* bstart = (unsigned*)(ws + 116864);
    unsigned* gcur   = (unsigned*)(ws + 117120);
    unsigned* copies = (unsigned*)(ws + 150976);
    unsigned* bkc    = (unsigned*)(ws + 150976);
    unsigned* bkpk   = (unsigned*)(ws + 950976);
    _Float16* h      = (_Float16*)(ws + 150976);
    unsigned* epk    = (unsigned*)(ws + 4950976);
    _Float16* g0h    = (_Float16*)(ws + 6550976);
    _Float16* g1h    = (_Float16*)(ws + 8950976);

    const int B = 256;

    hipLaunchKernelGGL(k_fused1, dim3(974), dim3(B), 0, stream,
                       x, W1, g0h, ei, E, copies, bcnt2d, N);
    hipLaunchKernelGGL(k_reduce, dim3(98), dim3(B), 0, stream,
                       copies, bcnt2d, dinv, bstart, gcur, off, (unsigned)E);

    hipLaunchKernelGGL(k_bucket, dim3(320), dim3(B), 0, stream,
                       row, col, ew, dinv, gcur, bkc, bkpk, E);
    hipLaunchKernelGGL(k_place, dim3(NBK), dim3(B), 0, stream, bkc, bkpk, bstart, off, epk, N);

    hipLaunchKernelGGL(k_agg96, dim3((N * 12 + B - 1) / B), dim3(B), 0, stream,
                       g0h, off, epk, dinv, b1, h, N);

    hipLaunchKernelGGL(k_gemm2, dim3((N + 63) / 64), dim3(B), 0, stream, h, W2, g1h, N);

    hipLaunchKernelGGL(k_agg40lsm, dim3((N + 49) / 50), dim3(B), 0, stream,
                       g1h, off, epk, dinv, b2, out, N);
}